// Round 1
// baseline (2812.663 us; speedup 1.0000x reference)
//
#include <hip/hip_runtime.h>
#include <hip/hip_bf16.h>

#define HID 64
#define BN_EPS 1e-5f

// ---------------- Kernel A: h0 = x @ W1 + b1  ([N,3]@[3,64]) ----------------
__global__ __launch_bounds__(256) void dense_in_k(
    const float* __restrict__ x, const float* __restrict__ W1,
    const float* __restrict__ b1, float* __restrict__ out, int N) {
  int t = blockIdx.x * 256 + threadIdx.x;
  if (t >= N * HID) return;
  int f = t & (HID - 1);
  int n = t >> 6;
  float x0 = x[n * 3 + 0], x1 = x[n * 3 + 1], x2 = x[n * 3 + 2];
  float acc = b1[f];
  acc = fmaf(x0, W1[0 * HID + f], acc);
  acc = fmaf(x1, W1[1 * HID + f], acc);
  acc = fmaf(x2, W1[2 * HID + f], acc);
  out[t] = acc;
}

// ---------------- SpMM: out[row] += vals * h[col]  (atomic scatter) ----------
// 16 threads per edge, each handles 4 features via float4 gather.
__global__ __launch_bounds__(256) void spmm_atomic_k(
    const int* __restrict__ row, const int* __restrict__ col,
    const float* __restrict__ vals, const float* __restrict__ h,
    float* __restrict__ out, int E) {
  int t = blockIdx.x * 256 + threadIdx.x;
  int e = t >> 4;
  if (e >= E) return;
  int p = (t & 15) * 4;
  int r = row[e], c = col[e];
  float v = vals[e];
  float4 hv = *reinterpret_cast<const float4*>(&h[c * HID + p]);
  float* o = &out[r * HID + p];
  unsafeAtomicAdd(o + 0, v * hv.x);
  unsafeAtomicAdd(o + 1, v * hv.y);
  unsafeAtomicAdd(o + 2, v * hv.z);
  unsafeAtomicAdd(o + 3, v * hv.w);
}

// ------------- BN1 + ReLU fused into h @ W2 + b2 ([N,64]@[64,64]) ------------
// 256 threads = 4 node-slots x 64 features; block covers 64 nodes.
__global__ __launch_bounds__(256) void bn_mm_k(
    const float* __restrict__ hin,
    const float* __restrict__ g, const float* __restrict__ be,
    const float* __restrict__ m, const float* __restrict__ v,
    const float* __restrict__ W2, const float* __restrict__ b2,
    float* __restrict__ out, int N) {
  __shared__ float sW[HID][HID];   // 16 KB
  __shared__ float sh[4][HID];     // 1 KB
  int tid = threadIdx.x;
  int f = tid & (HID - 1);
  int q = tid >> 6;  // 0..3
  for (int i = tid; i < HID * HID; i += 256) sW[i >> 6][i & (HID - 1)] = W2[i];
  float scale = g[f] * rsqrtf(v[f] + BN_EPS);
  float shift = fmaf(-m[f], scale, be[f]);
  float bias = b2[f];
  int nbase = blockIdx.x * 64;
  for (int it = 0; it < 16; ++it) {
    int n = nbase + it * 4 + q;
    __syncthreads();
    float hv = 0.f;
    if (n < N) hv = hin[n * HID + f];
    sh[q][f] = fmaxf(fmaf(hv, scale, shift), 0.f);
    __syncthreads();
    if (n < N) {
      float acc = bias;
#pragma unroll
      for (int k = 0; k < HID; ++k) acc = fmaf(sh[q][k], sW[k][f], acc);
      out[n * HID + f] = acc;
    }
  }
}

// -------- BN2 + ReLU fused into global mean-sum / max pool over nodes --------
__global__ __launch_bounds__(256) void bn_reduce_k(
    const float* __restrict__ hin,
    const float* __restrict__ g, const float* __restrict__ be,
    const float* __restrict__ m, const float* __restrict__ v,
    float* __restrict__ gsum, unsigned* __restrict__ gmax, int N) {
  int tid = threadIdx.x;
  int f = tid & (HID - 1);
  int q = tid >> 6;
  float scale = g[f] * rsqrtf(v[f] + BN_EPS);
  float shift = fmaf(-m[f], scale, be[f]);
  float s = 0.f, mx = 0.f;
  int stride = gridDim.x * 4;
  for (int n = blockIdx.x * 4 + q; n < N; n += stride) {
    float hv = fmaxf(fmaf(hin[n * HID + f], scale, shift), 0.f);
    s += hv;
    mx = fmaxf(mx, hv);
  }
  __shared__ float ls[4][HID], lm[4][HID];
  ls[q][f] = s;
  lm[q][f] = mx;
  __syncthreads();
  if (q == 0) {
    s = ls[0][f] + ls[1][f] + ls[2][f] + ls[3][f];
    mx = fmaxf(fmaxf(lm[0][f], lm[1][f]), fmaxf(lm[2][f], lm[3][f]));
    atomicAdd(&gsum[f], s);
    atomicMax(&gmax[f], __float_as_uint(mx));  // valid: values >= 0
  }
}

// ------------- final: out = concat(mean, max) @ Wc + bc  ([128]@[128,3]) -----
__global__ __launch_bounds__(128) void final_k(
    const float* __restrict__ gsum, const unsigned* __restrict__ gmax,
    const float* __restrict__ Wc, const float* __restrict__ bc,
    float* __restrict__ out, float invN) {
  __shared__ float red[128 * 3];
  int j = threadIdx.x;  // 0..127
  float gj = (j < HID) ? gsum[j] * invN : __uint_as_float(gmax[j - HID]);
#pragma unroll
  for (int c = 0; c < 3; ++c) red[j * 3 + c] = gj * Wc[j * 3 + c];
  __syncthreads();
  for (int off = 64; off >= 1; off >>= 1) {
    if (j < off) {
#pragma unroll
      for (int c = 0; c < 3; ++c) red[j * 3 + c] += red[(j + off) * 3 + c];
    }
    __syncthreads();
  }
  if (j < 3) out[j] = red[j] + bc[j];
}

extern "C" void kernel_launch(void* const* d_in, const int* in_sizes, int n_in,
                              void* d_out, int out_size, void* d_ws, size_t ws_size,
                              hipStream_t stream) {
  const float* x    = (const float*)d_in[0];
  const int*   row  = (const int*)d_in[1];
  const int*   col  = (const int*)d_in[2];
  const float* vals = (const float*)d_in[3];
  const float* W1   = (const float*)d_in[4];
  const float* b1   = (const float*)d_in[5];
  const float* g1   = (const float*)d_in[6];
  const float* be1  = (const float*)d_in[7];
  const float* m1   = (const float*)d_in[8];
  const float* v1   = (const float*)d_in[9];
  const float* W2   = (const float*)d_in[10];
  const float* b2   = (const float*)d_in[11];
  const float* g2   = (const float*)d_in[12];
  const float* be2  = (const float*)d_in[13];
  const float* m2   = (const float*)d_in[14];
  const float* v2   = (const float*)d_in[15];
  const float* Wc   = (const float*)d_in[16];
  const float* bc   = (const float*)d_in[17];
  float* out = (float*)d_out;

  const int N = in_sizes[0] / 3;
  const int E = in_sizes[1];

  float* wsA = (float*)d_ws;                 // [N,64]
  float* wsB = wsA + (size_t)N * HID;        // [N,64]
  float* gsum = wsB + (size_t)N * HID;       // [64]
  unsigned* gmax = (unsigned*)(gsum + HID);  // [64]

  // h0 = x@W1+b1 -> wsA
  dense_in_k<<<(N * HID + 255) / 256, 256, 0, stream>>>(x, W1, b1, wsA, N);
  // spmm1: wsB = A @ wsA
  hipMemsetAsync(wsB, 0, (size_t)N * HID * sizeof(float), stream);
  spmm_atomic_k<<<((size_t)E * 16 + 255) / 256, 256, 0, stream>>>(row, col, vals, wsA, wsB, E);
  // h2 = relu(bn1(wsB)) @ W2 + b2 -> wsA
  bn_mm_k<<<(N + 63) / 64, 256, 0, stream>>>(wsB, g1, be1, m1, v1, W2, b2, wsA, N);
  // spmm2: wsB = A @ wsA   (memset ordered after bn_mm on stream)
  hipMemsetAsync(wsB, 0, (size_t)N * HID * sizeof(float), stream);
  spmm_atomic_k<<<((size_t)E * 16 + 255) / 256, 256, 0, stream>>>(row, col, vals, wsA, wsB, E);
  // pool: mean-sum + max of relu(bn2(wsB))
  hipMemsetAsync(gsum, 0, 2 * HID * sizeof(float), stream);
  bn_reduce_k<<<1024, 256, 0, stream>>>(wsB, g2, be2, m2, v2, gsum, gmax, N);
  // out = concat(mean,max) @ Wc + bc
  final_k<<<1, 128, 0, stream>>>(gsum, gmax, Wc, bc, out, 1.0f / (float)N);
}

// Round 2
// 596.056 us; speedup vs baseline: 4.7188x; 4.7188x over previous
//
#include <hip/hip_runtime.h>
#include <hip/hip_bf16.h>

#define HID 64
#define BN_EPS 1e-5f

// ---------------- Kernel A: h0 = x @ W1 + b1  ([N,3]@[3,64]) ----------------
__global__ __launch_bounds__(256) void dense_in_k(
    const float* __restrict__ x, const float* __restrict__ W1,
    const float* __restrict__ b1, float* __restrict__ out, int N) {
  int t = blockIdx.x * 256 + threadIdx.x;
  if (t >= N * HID) return;
  int f = t & (HID - 1);
  int n = t >> 6;
  float x0 = x[n * 3 + 0], x1 = x[n * 3 + 1], x2 = x[n * 3 + 2];
  float acc = b1[f];
  acc = fmaf(x0, W1[0 * HID + f], acc);
  acc = fmaf(x1, W1[1 * HID + f], acc);
  acc = fmaf(x2, W1[2 * HID + f], acc);
  out[t] = acc;
}

// ---------------- CSR build: histogram -> scan -> scatter --------------------
__global__ __launch_bounds__(256) void hist_k(
    const int* __restrict__ row, int* __restrict__ counts, int E) {
  int t = blockIdx.x * 256 + threadIdx.x;
  if (t < E) atomicAdd(&counts[row[t]], 1);
}

// per-block (1024 counts) sum
__global__ __launch_bounds__(256) void scan1_k(
    const int* __restrict__ counts, int* __restrict__ bsum, int N) {
  __shared__ int sm[256];
  int t = threadIdx.x;
  int base = blockIdx.x * 1024 + t * 4;
  int s = 0;
#pragma unroll
  for (int j = 0; j < 4; ++j) { int i = base + j; if (i < N) s += counts[i]; }
  sm[t] = s;
  __syncthreads();
  for (int off = 128; off >= 1; off >>= 1) {
    if (t < off) sm[t] += sm[t + off];
    __syncthreads();
  }
  if (t == 0) bsum[blockIdx.x] = sm[0];
}

// exclusive scan of up-to-1024 block sums (single block)
__global__ __launch_bounds__(1024) void scan2_k(int* __restrict__ bsum, int nb) {
  __shared__ int sm[1024];
  int t = threadIdx.x;
  int orig = (t < nb) ? bsum[t] : 0;
  sm[t] = orig;
  __syncthreads();
  for (int off = 1; off < 1024; off <<= 1) {
    int v = 0;
    if (t >= off) v = sm[t - off];
    __syncthreads();
    sm[t] += v;
    __syncthreads();
  }
  if (t < nb) bsum[t] = sm[t] - orig;  // exclusive
}

// per-block exclusive scan + write rowptr and cursor
__global__ __launch_bounds__(256) void scan3_k(
    const int* __restrict__ counts, const int* __restrict__ bexc,
    int* __restrict__ rowptr, int* __restrict__ cursor, int N, int E) {
  __shared__ int sm[256];
  int t = threadIdx.x;
  int base = blockIdx.x * 1024 + t * 4;
  int c[4];
  int s = 0;
#pragma unroll
  for (int j = 0; j < 4; ++j) { int i = base + j; c[j] = (i < N) ? counts[i] : 0; s += c[j]; }
  int tot = s;
  sm[t] = tot;
  __syncthreads();
  for (int off = 1; off < 256; off <<= 1) {
    int v = 0;
    if (t >= off) v = sm[t - off];
    __syncthreads();
    sm[t] += v;
    __syncthreads();
  }
  int exc = sm[t] - tot + bexc[blockIdx.x];
#pragma unroll
  for (int j = 0; j < 4; ++j) {
    int i = base + j;
    if (i < N) {
      rowptr[i] = exc;
      cursor[i] = exc;
      if (i == N - 1) rowptr[N] = exc + c[j];  // == E
      exc += c[j];
    }
  }
}

// scatter edges into row-grouped order: cv[pos] = {col, val_bits}
__global__ __launch_bounds__(256) void scatter_k(
    const int* __restrict__ row, const int* __restrict__ col,
    const float* __restrict__ vals, int* __restrict__ cursor,
    int2* __restrict__ cv, int E) {
  int t = blockIdx.x * 256 + threadIdx.x;
  if (t >= E) return;
  int r = row[t];
  int pos = atomicAdd(&cursor[r], 1);
  cv[pos] = make_int2(col[t], __float_as_int(vals[t]));
}

// ---------------- SpMM (pull): one wave per row, lane = feature --------------
__global__ __launch_bounds__(256) void spmm_csr_k(
    const int* __restrict__ rowptr, const int2* __restrict__ cv,
    const float* __restrict__ h, float* __restrict__ out, int N) {
  int w = (blockIdx.x * 256 + threadIdx.x) >> 6;  // row id
  int lane = threadIdx.x & 63;                    // feature id
  if (w >= N) return;
  int s = rowptr[w], e = rowptr[w + 1];
  float acc = 0.f;
  for (int i = s; i < e; ++i) {
    int2 p = cv[i];  // broadcast: all lanes same address
    acc = fmaf(__int_as_float(p.y), h[(size_t)p.x * HID + lane], acc);
  }
  out[(size_t)w * HID + lane] = acc;
}

// ------------- BN1 + ReLU fused into h @ W2 + b2 ([N,64]@[64,64]) ------------
__global__ __launch_bounds__(256) void bn_mm_k(
    const float* __restrict__ hin,
    const float* __restrict__ g, const float* __restrict__ be,
    const float* __restrict__ m, const float* __restrict__ v,
    const float* __restrict__ W2, const float* __restrict__ b2,
    float* __restrict__ out, int N) {
  __shared__ float sW[HID][HID];   // 16 KB
  __shared__ float sh[4][HID];     // 1 KB
  int tid = threadIdx.x;
  int f = tid & (HID - 1);
  int q = tid >> 6;  // 0..3
  for (int i = tid; i < HID * HID; i += 256) sW[i >> 6][i & (HID - 1)] = W2[i];
  float scale = g[f] * rsqrtf(v[f] + BN_EPS);
  float shift = fmaf(-m[f], scale, be[f]);
  float bias = b2[f];
  int nbase = blockIdx.x * 64;
  for (int it = 0; it < 16; ++it) {
    int n = nbase + it * 4 + q;
    __syncthreads();
    float hv = 0.f;
    if (n < N) hv = hin[n * HID + f];
    sh[q][f] = fmaxf(fmaf(hv, scale, shift), 0.f);
    __syncthreads();
    if (n < N) {
      float acc = bias;
#pragma unroll
      for (int k = 0; k < HID; ++k) acc = fmaf(sh[q][k], sW[k][f], acc);
      out[n * HID + f] = acc;
    }
  }
}

// -------- BN2 + ReLU fused into global mean-sum / max pool over nodes --------
__global__ __launch_bounds__(256) void bn_reduce_k(
    const float* __restrict__ hin,
    const float* __restrict__ g, const float* __restrict__ be,
    const float* __restrict__ m, const float* __restrict__ v,
    float* __restrict__ gsum, unsigned* __restrict__ gmax, int N) {
  int tid = threadIdx.x;
  int f = tid & (HID - 1);
  int q = tid >> 6;
  float scale = g[f] * rsqrtf(v[f] + BN_EPS);
  float shift = fmaf(-m[f], scale, be[f]);
  float s = 0.f, mx = 0.f;
  int stride = gridDim.x * 4;
  for (int n = blockIdx.x * 4 + q; n < N; n += stride) {
    float hv = fmaxf(fmaf(hin[n * HID + f], scale, shift), 0.f);
    s += hv;
    mx = fmaxf(mx, hv);
  }
  __shared__ float ls[4][HID], lm[4][HID];
  ls[q][f] = s;
  lm[q][f] = mx;
  __syncthreads();
  if (q == 0) {
    s = ls[0][f] + ls[1][f] + ls[2][f] + ls[3][f];
    mx = fmaxf(fmaxf(lm[0][f], lm[1][f]), fmaxf(lm[2][f], lm[3][f]));
    atomicAdd(&gsum[f], s);
    atomicMax(&gmax[f], __float_as_uint(mx));  // valid: values >= 0
  }
}

// ------------- final: out = concat(mean, max) @ Wc + bc  ([128]@[128,3]) -----
__global__ __launch_bounds__(128) void final_k(
    const float* __restrict__ gsum, const unsigned* __restrict__ gmax,
    const float* __restrict__ Wc, const float* __restrict__ bc,
    float* __restrict__ out, float invN) {
  __shared__ float red[128 * 3];
  int j = threadIdx.x;  // 0..127
  float gj = (j < HID) ? gsum[j] * invN : __uint_as_float(gmax[j - HID]);
#pragma unroll
  for (int c = 0; c < 3; ++c) red[j * 3 + c] = gj * Wc[j * 3 + c];
  __syncthreads();
  for (int off = 64; off >= 1; off >>= 1) {
    if (j < off) {
#pragma unroll
      for (int c = 0; c < 3; ++c) red[j * 3 + c] += red[(j + off) * 3 + c];
    }
    __syncthreads();
  }
  if (j < 3) out[j] = red[j] + bc[j];
}

extern "C" void kernel_launch(void* const* d_in, const int* in_sizes, int n_in,
                              void* d_out, int out_size, void* d_ws, size_t ws_size,
                              hipStream_t stream) {
  const float* x    = (const float*)d_in[0];
  const int*   row  = (const int*)d_in[1];
  const int*   col  = (const int*)d_in[2];
  const float* vals = (const float*)d_in[3];
  const float* W1   = (const float*)d_in[4];
  const float* b1   = (const float*)d_in[5];
  const float* g1   = (const float*)d_in[6];
  const float* be1  = (const float*)d_in[7];
  const float* m1   = (const float*)d_in[8];
  const float* v1   = (const float*)d_in[9];
  const float* W2   = (const float*)d_in[10];
  const float* b2   = (const float*)d_in[11];
  const float* g2   = (const float*)d_in[12];
  const float* be2  = (const float*)d_in[13];
  const float* m2   = (const float*)d_in[14];
  const float* v2   = (const float*)d_in[15];
  const float* Wc   = (const float*)d_in[16];
  const float* bc   = (const float*)d_in[17];
  float* out = (float*)d_out;

  const int N = in_sizes[0] / 3;
  const int E = in_sizes[1];

  // ---- workspace layout (8B-aligned segments) ----
  float* wsA   = (float*)d_ws;                   // N*64 f32
  float* wsB   = wsA + (size_t)N * HID;          // N*64 f32
  int*   counts = (int*)(wsB + (size_t)N * HID); // N
  int*   rowptr = counts + N;                    // N+2 (pad to keep 8B align)
  int*   cursor = rowptr + (N + 2);              // N
  int*   bsum   = cursor + N;                    // 1024
  int2*  cv     = (int2*)(bsum + 1024);          // E
  float* gsum   = (float*)(cv + E);              // 64
  unsigned* gmax = (unsigned*)(gsum + HID);      // 64

  const int nbScan = (N + 1023) / 1024;

  // ---- build CSR (once; shared by both SpMMs) ----
  hipMemsetAsync(counts, 0, (size_t)N * sizeof(int), stream);
  hist_k<<<(E + 255) / 256, 256, 0, stream>>>(row, counts, E);
  scan1_k<<<nbScan, 256, 0, stream>>>(counts, bsum, N);
  scan2_k<<<1, 1024, 0, stream>>>(bsum, nbScan);
  scan3_k<<<nbScan, 256, 0, stream>>>(counts, bsum, rowptr, cursor, N, E);
  scatter_k<<<(E + 255) / 256, 256, 0, stream>>>(row, col, vals, cursor, cv, E);

  // ---- h0 = x@W1+b1 -> wsA ----
  dense_in_k<<<(N * HID + 255) / 256, 256, 0, stream>>>(x, W1, b1, wsA, N);
  // ---- spmm1: wsB = A @ wsA (pull, no atomics) ----
  spmm_csr_k<<<(N + 3) / 4, 256, 0, stream>>>(rowptr, cv, wsA, wsB, N);
  // ---- h2 = relu(bn1(wsB)) @ W2 + b2 -> wsA ----
  bn_mm_k<<<(N + 63) / 64, 256, 0, stream>>>(wsB, g1, be1, m1, v1, W2, b2, wsA, N);
  // ---- spmm2: wsB = A @ wsA ----
  spmm_csr_k<<<(N + 3) / 4, 256, 0, stream>>>(rowptr, cv, wsA, wsB, N);
  // ---- pool: mean-sum + max of relu(bn2(wsB)) ----
  hipMemsetAsync(gsum, 0, 2 * HID * sizeof(float), stream);
  bn_reduce_k<<<1024, 256, 0, stream>>>(wsB, g2, be2, m2, v2, gsum, gmax, N);
  // ---- out = concat(mean,max) @ Wc + bc ----
  final_k<<<1, 128, 0, stream>>>(gsum, gmax, Wc, bc, out, 1.0f / (float)N);
}

// Round 3
// 452.198 us; speedup vs baseline: 6.2200x; 1.3181x over previous
//
#include <hip/hip_runtime.h>
#include <hip/hip_bf16.h>

#define HID 64
#define BN_EPS 1e-5f

// ---------------- CSR build: histogram -> scan -> scatter --------------------
__global__ __launch_bounds__(256) void hist_k(
    const int* __restrict__ row, int* __restrict__ counts, int E) {
  int t = blockIdx.x * 256 + threadIdx.x;
  if (t < E) atomicAdd(&counts[row[t]], 1);
}

// per-block (1024 counts) sum
__global__ __launch_bounds__(256) void scan1_k(
    const int* __restrict__ counts, int* __restrict__ bsum, int N) {
  __shared__ int sm[256];
  int t = threadIdx.x;
  int base = blockIdx.x * 1024 + t * 4;
  int s = 0;
#pragma unroll
  for (int j = 0; j < 4; ++j) { int i = base + j; if (i < N) s += counts[i]; }
  sm[t] = s;
  __syncthreads();
  for (int off = 128; off >= 1; off >>= 1) {
    if (t < off) sm[t] += sm[t + off];
    __syncthreads();
  }
  if (t == 0) bsum[blockIdx.x] = sm[0];
}

// exclusive scan of up-to-1024 block sums (single block)
__global__ __launch_bounds__(1024) void scan2_k(int* __restrict__ bsum, int nb) {
  __shared__ int sm[1024];
  int t = threadIdx.x;
  int orig = (t < nb) ? bsum[t] : 0;
  sm[t] = orig;
  __syncthreads();
  for (int off = 1; off < 1024; off <<= 1) {
    int v = 0;
    if (t >= off) v = sm[t - off];
    __syncthreads();
    sm[t] += v;
    __syncthreads();
  }
  if (t < nb) bsum[t] = sm[t] - orig;  // exclusive
}

// per-block exclusive scan + write rowptr and cursor
__global__ __launch_bounds__(256) void scan3_k(
    const int* __restrict__ counts, const int* __restrict__ bexc,
    int* __restrict__ rowptr, int* __restrict__ cursor, int N, int E) {
  __shared__ int sm[256];
  int t = threadIdx.x;
  int base = blockIdx.x * 1024 + t * 4;
  int c[4];
  int s = 0;
#pragma unroll
  for (int j = 0; j < 4; ++j) { int i = base + j; c[j] = (i < N) ? counts[i] : 0; s += c[j]; }
  int tot = s;
  sm[t] = tot;
  __syncthreads();
  for (int off = 1; off < 256; off <<= 1) {
    int v = 0;
    if (t >= off) v = sm[t - off];
    __syncthreads();
    sm[t] += v;
    __syncthreads();
  }
  int exc = sm[t] - tot + bexc[blockIdx.x];
#pragma unroll
  for (int j = 0; j < 4; ++j) {
    int i = base + j;
    if (i < N) {
      rowptr[i] = exc;
      cursor[i] = exc;
      if (i == N - 1) rowptr[N] = exc + c[j];  // == E
      exc += c[j];
    }
  }
}

// scatter edges into row-grouped order: cv[pos] = {col, val_bits}
__global__ __launch_bounds__(256) void scatter_k(
    const int* __restrict__ row, const int* __restrict__ col,
    const float* __restrict__ vals, int* __restrict__ cursor,
    int2* __restrict__ cv, int E) {
  int t = blockIdx.x * 256 + threadIdx.x;
  if (t >= E) return;
  int r = row[t];
  int pos = atomicAdd(&cursor[r], 1);
  cv[pos] = make_int2(col[t], __float_as_int(vals[t]));
}

// ------ SpMM1 fused with layer-1 dense: out[r] = sum_e v * (x[c]@W1 + b1) ----
// one wave per row, lane = output feature; x[c] is a 12B wave-uniform load.
__global__ __launch_bounds__(256) void spmm1_fused_k(
    const int* __restrict__ rowptr, const int2* __restrict__ cv,
    const float* __restrict__ x, const float* __restrict__ W1,
    const float* __restrict__ b1, float* __restrict__ out, int N) {
  int w = (blockIdx.x * 256 + threadIdx.x) >> 6;  // row id
  int lane = threadIdx.x & 63;                    // feature id
  if (w >= N) return;
  float w0 = W1[0 * HID + lane], w1 = W1[1 * HID + lane],
        w2 = W1[2 * HID + lane], bb = b1[lane];
  int s = rowptr[w], e = rowptr[w + 1];
  float acc = 0.f;
  int i = s;
  for (; i + 4 <= e; i += 4) {
    int2 pa = cv[i + 0], pb = cv[i + 1], pc = cv[i + 2], pd = cv[i + 3];
    float xa0 = x[pa.x * 3], xa1 = x[pa.x * 3 + 1], xa2 = x[pa.x * 3 + 2];
    float xb0 = x[pb.x * 3], xb1 = x[pb.x * 3 + 1], xb2 = x[pb.x * 3 + 2];
    float xc0 = x[pc.x * 3], xc1 = x[pc.x * 3 + 1], xc2 = x[pc.x * 3 + 2];
    float xd0 = x[pd.x * 3], xd1 = x[pd.x * 3 + 1], xd2 = x[pd.x * 3 + 2];
    float ha = fmaf(xa2, w2, fmaf(xa1, w1, fmaf(xa0, w0, bb)));
    float hb = fmaf(xb2, w2, fmaf(xb1, w1, fmaf(xb0, w0, bb)));
    float hc = fmaf(xc2, w2, fmaf(xc1, w1, fmaf(xc0, w0, bb)));
    float hd = fmaf(xd2, w2, fmaf(xd1, w1, fmaf(xd0, w0, bb)));
    acc = fmaf(__int_as_float(pa.y), ha, acc);
    acc = fmaf(__int_as_float(pb.y), hb, acc);
    acc = fmaf(__int_as_float(pc.y), hc, acc);
    acc = fmaf(__int_as_float(pd.y), hd, acc);
  }
  for (; i < e; ++i) {
    int2 p = cv[i];
    float x0 = x[p.x * 3], x1 = x[p.x * 3 + 1], x2 = x[p.x * 3 + 2];
    float hv = fmaf(x2, w2, fmaf(x1, w1, fmaf(x0, w0, bb)));
    acc = fmaf(__int_as_float(p.y), hv, acc);
  }
  out[(size_t)w * HID + lane] = acc;
}

// ------------- BN1 + ReLU fused into h @ W2 + b2 ([N,64]@[64,64]) ------------
__global__ __launch_bounds__(256) void bn_mm_k(
    const float* __restrict__ hin,
    const float* __restrict__ g, const float* __restrict__ be,
    const float* __restrict__ m, const float* __restrict__ v,
    const float* __restrict__ W2, const float* __restrict__ b2,
    float* __restrict__ out, int N) {
  __shared__ float sW[HID][HID];   // 16 KB
  __shared__ float sh[4][HID];     // 1 KB
  int tid = threadIdx.x;
  int f = tid & (HID - 1);
  int q = tid >> 6;  // 0..3
  for (int i = tid; i < HID * HID; i += 256) sW[i >> 6][i & (HID - 1)] = W2[i];
  float scale = g[f] * rsqrtf(v[f] + BN_EPS);
  float shift = fmaf(-m[f], scale, be[f]);
  float bias = b2[f];
  int nbase = blockIdx.x * 64;
  for (int it = 0; it < 16; ++it) {
    int n = nbase + it * 4 + q;
    __syncthreads();
    float hv = 0.f;
    if (n < N) hv = hin[n * HID + f];
    sh[q][f] = fmaxf(fmaf(hv, scale, shift), 0.f);
    __syncthreads();
    if (n < N) {
      float acc = bias;
#pragma unroll
      for (int k = 0; k < HID; ++k) acc = fmaf(sh[q][k], sW[k][f], acc);
      out[n * HID + f] = acc;
    }
  }
}

// ---- SpMM2 fused with BN2 + ReLU + global mean-sum / max pool ---------------
// grid-stride over rows; one wave per row; block-level reduce then one
// atomicAdd / atomicMax per feature per block.
__global__ __launch_bounds__(256) void spmm2_pool_k(
    const int* __restrict__ rowptr, const int2* __restrict__ cv,
    const float* __restrict__ h,
    const float* __restrict__ g, const float* __restrict__ be,
    const float* __restrict__ m, const float* __restrict__ v,
    float* __restrict__ gsum, unsigned* __restrict__ gmax, int N) {
  int lane = threadIdx.x & 63;
  int wid = threadIdx.x >> 6;  // 0..3
  float scale = g[lane] * rsqrtf(v[lane] + BN_EPS);
  float shift = fmaf(-m[lane], scale, be[lane]);
  float psum = 0.f, pmax = 0.f;
  int stride = gridDim.x * 4;
  for (int r = blockIdx.x * 4 + wid; r < N; r += stride) {
    int s = rowptr[r], e = rowptr[r + 1];
    float acc = 0.f;
    int i = s;
    for (; i + 4 <= e; i += 4) {
      int2 pa = cv[i + 0], pb = cv[i + 1], pc = cv[i + 2], pd = cv[i + 3];
      float a0 = h[(size_t)pa.x * HID + lane];
      float a1 = h[(size_t)pb.x * HID + lane];
      float a2 = h[(size_t)pc.x * HID + lane];
      float a3 = h[(size_t)pd.x * HID + lane];
      acc = fmaf(__int_as_float(pa.y), a0, acc);
      acc = fmaf(__int_as_float(pb.y), a1, acc);
      acc = fmaf(__int_as_float(pc.y), a2, acc);
      acc = fmaf(__int_as_float(pd.y), a3, acc);
    }
    for (; i < e; ++i) {
      int2 p = cv[i];
      acc = fmaf(__int_as_float(p.y), h[(size_t)p.x * HID + lane], acc);
    }
    float hv = fmaxf(fmaf(acc, scale, shift), 0.f);
    psum += hv;
    pmax = fmaxf(pmax, hv);
  }
  __shared__ float ls[4][HID], lm[4][HID];
  ls[wid][lane] = psum;
  lm[wid][lane] = pmax;
  __syncthreads();
  if (wid == 0) {
    float s4 = ls[0][lane] + ls[1][lane] + ls[2][lane] + ls[3][lane];
    float m4 = fmaxf(fmaxf(lm[0][lane], lm[1][lane]),
                     fmaxf(lm[2][lane], lm[3][lane]));
    atomicAdd(&gsum[lane], s4);
    atomicMax(&gmax[lane], __float_as_uint(m4));  // valid: values >= 0
  }
}

// ------------- final: out = concat(mean, max) @ Wc + bc  ([128]@[128,3]) -----
__global__ __launch_bounds__(128) void final_k(
    const float* __restrict__ gsum, const unsigned* __restrict__ gmax,
    const float* __restrict__ Wc, const float* __restrict__ bc,
    float* __restrict__ out, float invN) {
  __shared__ float red[128 * 3];
  int j = threadIdx.x;  // 0..127
  float gj = (j < HID) ? gsum[j] * invN : __uint_as_float(gmax[j - HID]);
#pragma unroll
  for (int c = 0; c < 3; ++c) red[j * 3 + c] = gj * Wc[j * 3 + c];
  __syncthreads();
  for (int off = 64; off >= 1; off >>= 1) {
    if (j < off) {
#pragma unroll
      for (int c = 0; c < 3; ++c) red[j * 3 + c] += red[(j + off) * 3 + c];
    }
    __syncthreads();
  }
  if (j < 3) out[j] = red[j] + bc[j];
}

extern "C" void kernel_launch(void* const* d_in, const int* in_sizes, int n_in,
                              void* d_out, int out_size, void* d_ws, size_t ws_size,
                              hipStream_t stream) {
  const float* x    = (const float*)d_in[0];
  const int*   row  = (const int*)d_in[1];
  const int*   col  = (const int*)d_in[2];
  const float* vals = (const float*)d_in[3];
  const float* W1   = (const float*)d_in[4];
  const float* b1   = (const float*)d_in[5];
  const float* g1   = (const float*)d_in[6];
  const float* be1  = (const float*)d_in[7];
  const float* m1   = (const float*)d_in[8];
  const float* v1   = (const float*)d_in[9];
  const float* W2   = (const float*)d_in[10];
  const float* b2   = (const float*)d_in[11];
  const float* g2   = (const float*)d_in[12];
  const float* be2  = (const float*)d_in[13];
  const float* m2   = (const float*)d_in[14];
  const float* v2   = (const float*)d_in[15];
  const float* Wc   = (const float*)d_in[16];
  const float* bc   = (const float*)d_in[17];
  float* out = (float*)d_out;

  const int N = in_sizes[0] / 3;
  const int E = in_sizes[1];

  // ---- workspace layout ----
  float* wsA   = (float*)d_ws;                   // N*64 f32 (bn_mm out)
  float* wsB   = wsA + (size_t)N * HID;          // N*64 f32 (spmm1 out)
  int*   counts = (int*)(wsB + (size_t)N * HID); // N
  int*   rowptr = counts + N;                    // N+2
  int*   cursor = rowptr + (N + 2);              // N
  int*   bsum   = cursor + N;                    // 1024
  int2*  cv     = (int2*)(bsum + 1024);          // E
  float* gsum   = (float*)(cv + E);              // 64
  unsigned* gmax = (unsigned*)(gsum + HID);      // 64

  const int nbScan = (N + 1023) / 1024;

  // ---- build CSR (once; shared by both SpMMs) ----
  hipMemsetAsync(counts, 0, (size_t)N * sizeof(int), stream);
  hist_k<<<(E + 255) / 256, 256, 0, stream>>>(row, counts, E);
  scan1_k<<<nbScan, 256, 0, stream>>>(counts, bsum, N);
  scan2_k<<<1, 1024, 0, stream>>>(bsum, nbScan);
  scan3_k<<<nbScan, 256, 0, stream>>>(counts, bsum, rowptr, cursor, N, E);
  scatter_k<<<(E + 255) / 256, 256, 0, stream>>>(row, col, vals, cursor, cv, E);

  // ---- spmm1 (fused dense-in): wsB = A @ (x@W1+b1) ----
  spmm1_fused_k<<<(N + 3) / 4, 256, 0, stream>>>(rowptr, cv, x, W1, b1, wsB, N);
  // ---- wsA = relu(bn1(wsB)) @ W2 + b2 ----
  bn_mm_k<<<(N + 63) / 64, 256, 0, stream>>>(wsB, g1, be1, m1, v1, W2, b2, wsA, N);
  // ---- spmm2 fused with BN2+ReLU+pool ----
  hipMemsetAsync(gsum, 0, 2 * HID * sizeof(float), stream);
  spmm2_pool_k<<<1024, 256, 0, stream>>>(rowptr, cv, wsA, g2, be2, m2, v2, gsum, gmax, N);
  // ---- out = concat(mean,max) @ Wc + bc ----
  final_k<<<1, 128, 0, stream>>>(gsum, gmax, Wc, bc, out, 1.0f / (float)N);
}

// Round 4
// 332.629 us; speedup vs baseline: 8.4559x; 1.3595x over previous
//
#include <hip/hip_runtime.h>
#include <hip/hip_bf16.h>

#define HID 64
#define BN_EPS 1e-5f
#define BROWS 256          // rows per bucket
#define MAXB 512           // max buckets (N <= 131072)
#define BATCH 8192         // edges per pass-A block
#define CAP 8192           // pass-B LDS staging slots

// ---------------- bucket histogram (LDS pre-aggregated) ----------------------
__global__ __launch_bounds__(256) void bhist_k(
    const int* __restrict__ row, int* __restrict__ bhist, int E, int NB) {
  __shared__ int lcnt[MAXB];
  for (int i = threadIdx.x; i < MAXB; i += 256) lcnt[i] = 0;
  __syncthreads();
  int stride = gridDim.x * 256;
  for (int i = blockIdx.x * 256 + threadIdx.x; i < E; i += stride)
    atomicAdd(&lcnt[row[i] >> 8], 1);
  __syncthreads();
  for (int i = threadIdx.x; i < NB; i += 256)
    if (lcnt[i]) atomicAdd(&bhist[i], lcnt[i]);
}

// ---------------- bucket exclusive scan (single block) -----------------------
__global__ __launch_bounds__(256) void bscan_k(
    const int* __restrict__ bhist, int* __restrict__ bbase,
    int* __restrict__ bcur, int* __restrict__ rowptr, int NB, int N, int E) {
  __shared__ int scn[512];
  __shared__ int orig[512];
  int t = threadIdx.x;
  int i0 = t, i1 = t + 256;
  int v0 = (i0 < NB) ? bhist[i0] : 0;
  int v1 = (i1 < NB) ? bhist[i1] : 0;
  scn[i0] = v0; orig[i0] = v0;
  scn[i1] = v1; orig[i1] = v1;
  __syncthreads();
  for (int off = 1; off < 512; off <<= 1) {
    int a0 = (i0 >= off) ? scn[i0 - off] : 0;
    int a1 = (i1 >= off) ? scn[i1 - off] : 0;
    __syncthreads();
    scn[i0] += a0; scn[i1] += a1;
    __syncthreads();
  }
  if (i0 < NB) { int e = scn[i0] - orig[i0]; bbase[i0] = e; bcur[i0] = e; }
  if (i1 < NB) { int e = scn[i1] - orig[i1]; bbase[i1] = e; bcur[i1] = e; }
  if (t == 0) { bbase[NB] = E; rowptr[N] = E; }
}

// ------- pass A: LDS-staged binning of edges into bucket regions -------------
// packed entry: .x = (localrow<<17) | col,  .y = val bits
__global__ __launch_bounds__(256) void bucketA_k(
    const int* __restrict__ row, const int* __restrict__ col,
    const float* __restrict__ vals, int* __restrict__ bcur,
    int2* __restrict__ bucketed, int E, int NB) {
  __shared__ int cnt[512];
  __shared__ int scn[512];
  __shared__ int cnt2[512];
  __shared__ int gbase[512];
  __shared__ int2 stg[BATCH];
  __shared__ unsigned short stgb[BATCH];
  int t = threadIdx.x;
  int start = blockIdx.x * BATCH;
  for (int i = t; i < 512; i += 256) { cnt[i] = 0; }
  __syncthreads();
  // sub-pass 1: count
#pragma unroll
  for (int k = 0; k < BATCH / 256; ++k) {
    int i = start + k * 256 + t;
    if (i < E) atomicAdd(&cnt[row[i] >> 8], 1);
  }
  __syncthreads();
  // scan (512, two indices per thread)
  int i0 = t, i1 = t + 256;
  scn[i0] = cnt[i0]; scn[i1] = cnt[i1];
  __syncthreads();
  for (int off = 1; off < 512; off <<= 1) {
    int a0 = (i0 >= off) ? scn[i0 - off] : 0;
    int a1 = (i1 >= off) ? scn[i1 - off] : 0;
    __syncthreads();
    scn[i0] += a0; scn[i1] += a1;
    __syncthreads();
  }
  // local bases + global reservations
  cnt2[i0] = scn[i0] - cnt[i0];
  cnt2[i1] = scn[i1] - cnt[i1];
  for (int b = t; b < NB; b += 256)
    if (cnt[b] > 0) gbase[b] = atomicAdd(&bcur[b], cnt[b]);
  __syncthreads();
  // sub-pass 2: place into LDS
#pragma unroll
  for (int k = 0; k < BATCH / 256; ++k) {
    int i = start + k * 256 + t;
    if (i < E) {
      int r = row[i];
      int b = r >> 8;
      int pos = atomicAdd(&cnt2[b], 1);
      stg[pos] = make_int2(((r & 255) << 17) | col[i], __float_as_int(vals[i]));
      stgb[pos] = (unsigned short)b;
    }
  }
  __syncthreads();
  // flush coalesced
  int m = min(BATCH, E - start);
  for (int s = t; s < m; s += 256) {
    int b = stgb[s];
    int lbase = scn[b] - cnt[b];
    bucketed[gbase[b] + (s - lbase)] = stg[s];
  }
}

// ------- pass B: per-bucket LDS sort by row; write cv + rowptr ---------------
__global__ __launch_bounds__(256) void bucketB_k(
    const int2* __restrict__ bucketed, const int* __restrict__ bbase,
    int2* __restrict__ cv, int* __restrict__ rowptr, int N) {
  __shared__ int rcnt[BROWS];
  __shared__ int scn[BROWS];
  __shared__ int rcur[BROWS];
  __shared__ int2 stg[CAP];
  int b = blockIdx.x;
  int t = threadIdx.x;
  int base = bbase[b], cnt = bbase[b + 1] - base;
  int rows = min(BROWS, N - b * BROWS);
  rcnt[t] = 0;
  __syncthreads();
  for (int i = t; i < cnt; i += 256) {
    int2 e = bucketed[base + i];
    atomicAdd(&rcnt[e.x >> 17], 1);
  }
  __syncthreads();
  scn[t] = rcnt[t];
  __syncthreads();
  for (int off = 1; off < 256; off <<= 1) {
    int v = (t >= off) ? scn[t - off] : 0;
    __syncthreads();
    scn[t] += v;
    __syncthreads();
  }
  int excl = scn[t] - rcnt[t];
  rcur[t] = excl;
  if (t < rows) rowptr[b * BROWS + t] = base + excl;
  __syncthreads();
  for (int i = t; i < cnt; i += 256) {
    int2 e = bucketed[base + i];
    int pos = atomicAdd(&rcur[e.x >> 17], 1);
    if (pos < CAP) stg[pos] = make_int2(e.x & 0x1FFFF, e.y);
  }
  __syncthreads();
  for (int i = t; i < cnt; i += 256) cv[base + i] = stg[i];
}

// ------ SpMM1 fused with layer-1 dense: out[r] = sum_e v * (x[c]@W1 + b1) ----
__global__ __launch_bounds__(256) void spmm1_fused_k(
    const int* __restrict__ rowptr, const int2* __restrict__ cv,
    const float* __restrict__ x, const float* __restrict__ W1,
    const float* __restrict__ b1, float* __restrict__ out, int N) {
  int w = (blockIdx.x * 256 + threadIdx.x) >> 6;
  int lane = threadIdx.x & 63;
  if (w >= N) return;
  float w0 = W1[0 * HID + lane], w1 = W1[1 * HID + lane],
        w2 = W1[2 * HID + lane], bb = b1[lane];
  int s = rowptr[w], e = rowptr[w + 1];
  float acc = 0.f;
  int i = s;
  for (; i + 8 <= e; i += 8) {
    int2 p[8];
#pragma unroll
    for (int j = 0; j < 8; ++j) p[j] = cv[i + j];
    float xv[8][3];
#pragma unroll
    for (int j = 0; j < 8; ++j) {
      int c3 = p[j].x * 3;
      xv[j][0] = x[c3]; xv[j][1] = x[c3 + 1]; xv[j][2] = x[c3 + 2];
    }
#pragma unroll
    for (int j = 0; j < 8; ++j) {
      float hv = fmaf(xv[j][2], w2, fmaf(xv[j][1], w1, fmaf(xv[j][0], w0, bb)));
      acc = fmaf(__int_as_float(p[j].y), hv, acc);
    }
  }
  for (; i < e; ++i) {
    int2 p = cv[i];
    float x0 = x[p.x * 3], x1 = x[p.x * 3 + 1], x2 = x[p.x * 3 + 2];
    float hv = fmaf(x2, w2, fmaf(x1, w1, fmaf(x0, w0, bb)));
    acc = fmaf(__int_as_float(p.y), hv, acc);
  }
  out[(size_t)w * HID + lane] = acc;
}

// ------------- BN1 + ReLU fused into h @ W2 + b2; bf16 output ---------------
__global__ __launch_bounds__(256) void bn_mm_k(
    const float* __restrict__ hin,
    const float* __restrict__ g, const float* __restrict__ be,
    const float* __restrict__ m, const float* __restrict__ v,
    const float* __restrict__ W2, const float* __restrict__ b2,
    __hip_bfloat16* __restrict__ out, int N) {
  __shared__ float sW[HID][HID];
  __shared__ float sh[4][HID];
  int tid = threadIdx.x;
  int f = tid & (HID - 1);
  int q = tid >> 6;
  for (int i = tid; i < HID * HID; i += 256) sW[i >> 6][i & (HID - 1)] = W2[i];
  float scale = g[f] * rsqrtf(v[f] + BN_EPS);
  float shift = fmaf(-m[f], scale, be[f]);
  float bias = b2[f];
  int nbase = blockIdx.x * 64;
  for (int it = 0; it < 16; ++it) {
    int n = nbase + it * 4 + q;
    __syncthreads();
    float hv = 0.f;
    if (n < N) hv = hin[n * HID + f];
    sh[q][f] = fmaxf(fmaf(hv, scale, shift), 0.f);
    __syncthreads();
    if (n < N) {
      float acc = bias;
#pragma unroll
      for (int k = 0; k < HID; ++k) acc = fmaf(sh[q][k], sW[k][f], acc);
      out[(size_t)n * HID + f] = __float2bfloat16(acc);
    }
  }
}

// ---- SpMM2 (bf16 gather) fused with BN2 + ReLU + mean/max pool --------------
__global__ __launch_bounds__(256) void spmm2_pool_k(
    const int* __restrict__ rowptr, const int2* __restrict__ cv,
    const __hip_bfloat16* __restrict__ h,
    const float* __restrict__ g, const float* __restrict__ be,
    const float* __restrict__ m, const float* __restrict__ v,
    float* __restrict__ gsum, unsigned* __restrict__ gmax, int N) {
  int lane = threadIdx.x & 63;
  int wid = threadIdx.x >> 6;
  float scale = g[lane] * rsqrtf(v[lane] + BN_EPS);
  float shift = fmaf(-m[lane], scale, be[lane]);
  float psum = 0.f, pmax = 0.f;
  int stride = gridDim.x * 4;
  for (int r = blockIdx.x * 4 + wid; r < N; r += stride) {
    int s = rowptr[r], e = rowptr[r + 1];
    float acc = 0.f;
    int i = s;
    for (; i + 8 <= e; i += 8) {
      int2 p[8];
#pragma unroll
      for (int j = 0; j < 8; ++j) p[j] = cv[i + j];
      float a[8];
#pragma unroll
      for (int j = 0; j < 8; ++j)
        a[j] = __bfloat162float(h[(size_t)p[j].x * HID + lane]);
#pragma unroll
      for (int j = 0; j < 8; ++j)
        acc = fmaf(__int_as_float(p[j].y), a[j], acc);
    }
    for (; i < e; ++i) {
      int2 p = cv[i];
      acc = fmaf(__int_as_float(p.y),
                 __bfloat162float(h[(size_t)p.x * HID + lane]), acc);
    }
    float hv = fmaxf(fmaf(acc, scale, shift), 0.f);
    psum += hv;
    pmax = fmaxf(pmax, hv);
  }
  __shared__ float ls[4][HID], lm[4][HID];
  ls[wid][lane] = psum;
  lm[wid][lane] = pmax;
  __syncthreads();
  if (wid == 0) {
    float s4 = ls[0][lane] + ls[1][lane] + ls[2][lane] + ls[3][lane];
    float m4 = fmaxf(fmaxf(lm[0][lane], lm[1][lane]),
                     fmaxf(lm[2][lane], lm[3][lane]));
    atomicAdd(&gsum[lane], s4);
    atomicMax(&gmax[lane], __float_as_uint(m4));
  }
}

// ------------- final: out = concat(mean, max) @ Wc + bc ----------------------
__global__ __launch_bounds__(128) void final_k(
    const float* __restrict__ gsum, const unsigned* __restrict__ gmax,
    const float* __restrict__ Wc, const float* __restrict__ bc,
    float* __restrict__ out, float invN) {
  __shared__ float red[128 * 3];
  int j = threadIdx.x;
  float gj = (j < HID) ? gsum[j] * invN : __uint_as_float(gmax[j - HID]);
#pragma unroll
  for (int c = 0; c < 3; ++c) red[j * 3 + c] = gj * Wc[j * 3 + c];
  __syncthreads();
  for (int off = 64; off >= 1; off >>= 1) {
    if (j < off) {
#pragma unroll
      for (int c = 0; c < 3; ++c) red[j * 3 + c] += red[(j + off) * 3 + c];
    }
    __syncthreads();
  }
  if (j < 3) out[j] = red[j] + bc[j];
}

extern "C" void kernel_launch(void* const* d_in, const int* in_sizes, int n_in,
                              void* d_out, int out_size, void* d_ws, size_t ws_size,
                              hipStream_t stream) {
  const float* x    = (const float*)d_in[0];
  const int*   row  = (const int*)d_in[1];
  const int*   col  = (const int*)d_in[2];
  const float* vals = (const float*)d_in[3];
  const float* W1   = (const float*)d_in[4];
  const float* b1   = (const float*)d_in[5];
  const float* g1   = (const float*)d_in[6];
  const float* be1  = (const float*)d_in[7];
  const float* m1   = (const float*)d_in[8];
  const float* v1   = (const float*)d_in[9];
  const float* W2   = (const float*)d_in[10];
  const float* b2   = (const float*)d_in[11];
  const float* g2   = (const float*)d_in[12];
  const float* be2  = (const float*)d_in[13];
  const float* m2   = (const float*)d_in[14];
  const float* v2   = (const float*)d_in[15];
  const float* Wc   = (const float*)d_in[16];
  const float* bc   = (const float*)d_in[17];
  float* out = (float*)d_out;

  const int N = in_sizes[0] / 3;
  const int E = in_sizes[1];
  const int NB = (N + BROWS - 1) / BROWS;

  // ---- workspace layout ----
  float* wsB = (float*)d_ws;                                  // N*64 f32 (spmm1 out)
  __hip_bfloat16* wsA = (__hip_bfloat16*)(wsB + (size_t)N * HID);  // N*64 bf16 (bn_mm out)
  int2* bucketed = (int2*)(wsA + (size_t)N * HID);            // E
  int2* cv = bucketed + E;                                    // E
  int* rowptr = (int*)(cv + E);                               // N+2
  int* bhist = rowptr + (N + 2);                              // MAXB
  int* bbase = bhist + MAXB;                                  // MAXB+1
  int* bcur  = bbase + MAXB + 1;                              // MAXB
  float* gsum = (float*)(bcur + MAXB + 1);                    // 64
  unsigned* gmax = (unsigned*)(gsum + HID);                   // 64

  // ---- build row-sorted edge list (bucketed LDS sort, coalesced writes) ----
  hipMemsetAsync(bhist, 0, MAXB * sizeof(int), stream);
  bhist_k<<<512, 256, 0, stream>>>(row, bhist, E, NB);
  bscan_k<<<1, 256, 0, stream>>>(bhist, bbase, bcur, rowptr, NB, N, E);
  bucketA_k<<<(E + BATCH - 1) / BATCH, 256, 0, stream>>>(row, col, vals, bcur, bucketed, E, NB);
  bucketB_k<<<NB, 256, 0, stream>>>(bucketed, bbase, cv, rowptr, N);

  // ---- spmm1 (fused dense-in): wsB = A @ (x@W1+b1) ----
  spmm1_fused_k<<<(N + 3) / 4, 256, 0, stream>>>(rowptr, cv, x, W1, b1, wsB, N);
  // ---- wsA = bf16( relu(bn1(wsB)) @ W2 + b2 ) ----
  bn_mm_k<<<(N + 63) / 64, 256, 0, stream>>>(wsB, g1, be1, m1, v1, W2, b2, wsA, N);
  // ---- spmm2 fused with BN2+ReLU+pool (bf16 gather) ----
  hipMemsetAsync(gsum, 0, 2 * HID * sizeof(float), stream);
  spmm2_pool_k<<<2048, 256, 0, stream>>>(rowptr, cv, wsA, g2, be2, m2, v2, gsum, gmax, N);
  // ---- out = concat(mean,max) @ Wc + bc ----
  final_k<<<1, 128, 0, stream>>>(gsum, gmax, Wc, bc, out, 1.0f / (float)N);
}

// Round 5
// 264.305 us; speedup vs baseline: 10.6417x; 1.2585x over previous
//
#include <hip/hip_runtime.h>
#include <hip/hip_bf16.h>

#define HID 64
#define BN_EPS 1e-5f
#define BROWS 256          // rows per bucket
#define MAXB 512           // max buckets (N <= 131072)
#define BATCH 8192         // edges per pass-A block
#define CAP 8192           // pass-B LDS staging slots

// ---------------- bucket histogram (LDS pre-aggregated) ----------------------
__global__ __launch_bounds__(256) void bhist_k(
    const int* __restrict__ row, int* __restrict__ bhist, int E, int NB) {
  __shared__ int lcnt[MAXB];
  for (int i = threadIdx.x; i < MAXB; i += 256) lcnt[i] = 0;
  __syncthreads();
  int stride = gridDim.x * 256;
  for (int i = blockIdx.x * 256 + threadIdx.x; i < E; i += stride)
    atomicAdd(&lcnt[row[i] >> 8], 1);
  __syncthreads();
  for (int i = threadIdx.x; i < NB; i += 256)
    if (lcnt[i]) atomicAdd(&bhist[i], lcnt[i]);
}

// ---------------- bucket exclusive scan (single block) -----------------------
__global__ __launch_bounds__(256) void bscan_k(
    const int* __restrict__ bhist, int* __restrict__ bbase,
    int* __restrict__ bcur, int* __restrict__ rowptr, int NB, int N, int E) {
  __shared__ int scn[512];
  __shared__ int orig[512];
  int t = threadIdx.x;
  int i0 = t, i1 = t + 256;
  int v0 = (i0 < NB) ? bhist[i0] : 0;
  int v1 = (i1 < NB) ? bhist[i1] : 0;
  scn[i0] = v0; orig[i0] = v0;
  scn[i1] = v1; orig[i1] = v1;
  __syncthreads();
  for (int off = 1; off < 512; off <<= 1) {
    int a0 = (i0 >= off) ? scn[i0 - off] : 0;
    int a1 = (i1 >= off) ? scn[i1 - off] : 0;
    __syncthreads();
    scn[i0] += a0; scn[i1] += a1;
    __syncthreads();
  }
  if (i0 < NB) { int e = scn[i0] - orig[i0]; bbase[i0] = e; bcur[i0] = e; }
  if (i1 < NB) { int e = scn[i1] - orig[i1]; bbase[i1] = e; bcur[i1] = e; }
  if (t == 0) { bbase[NB] = E; rowptr[N] = E; }
}

// ------- pass A: LDS-staged binning of edges into bucket regions -------------
// packed entry: .x = (localrow<<17) | col,  .y = val bits
__global__ __launch_bounds__(256) void bucketA_k(
    const int* __restrict__ row, const int* __restrict__ col,
    const float* __restrict__ vals, int* __restrict__ bcur,
    int2* __restrict__ bucketed, int E, int NB) {
  __shared__ int cnt[512];
  __shared__ int scn[512];
  __shared__ int cnt2[512];
  __shared__ int gbase[512];
  __shared__ int2 stg[BATCH];
  __shared__ unsigned short stgb[BATCH];
  int t = threadIdx.x;
  int start = blockIdx.x * BATCH;
  for (int i = t; i < 512; i += 256) { cnt[i] = 0; }
  __syncthreads();
#pragma unroll
  for (int k = 0; k < BATCH / 256; ++k) {
    int i = start + k * 256 + t;
    if (i < E) atomicAdd(&cnt[row[i] >> 8], 1);
  }
  __syncthreads();
  int i0 = t, i1 = t + 256;
  scn[i0] = cnt[i0]; scn[i1] = cnt[i1];
  __syncthreads();
  for (int off = 1; off < 512; off <<= 1) {
    int a0 = (i0 >= off) ? scn[i0 - off] : 0;
    int a1 = (i1 >= off) ? scn[i1 - off] : 0;
    __syncthreads();
    scn[i0] += a0; scn[i1] += a1;
    __syncthreads();
  }
  cnt2[i0] = scn[i0] - cnt[i0];
  cnt2[i1] = scn[i1] - cnt[i1];
  for (int b = t; b < NB; b += 256)
    if (cnt[b] > 0) gbase[b] = atomicAdd(&bcur[b], cnt[b]);
  __syncthreads();
#pragma unroll
  for (int k = 0; k < BATCH / 256; ++k) {
    int i = start + k * 256 + t;
    if (i < E) {
      int r = row[i];
      int b = r >> 8;
      int pos = atomicAdd(&cnt2[b], 1);
      stg[pos] = make_int2(((r & 255) << 17) | col[i], __float_as_int(vals[i]));
      stgb[pos] = (unsigned short)b;
    }
  }
  __syncthreads();
  int m = min(BATCH, E - start);
  for (int s = t; s < m; s += 256) {
    int b = stgb[s];
    int lbase = scn[b] - cnt[b];
    bucketed[gbase[b] + (s - lbase)] = stg[s];
  }
}

// ------- pass B: per-bucket LDS sort by row; write cv + rowptr ---------------
__global__ __launch_bounds__(256) void bucketB_k(
    const int2* __restrict__ bucketed, const int* __restrict__ bbase,
    int2* __restrict__ cv, int* __restrict__ rowptr, int N) {
  __shared__ int rcnt[BROWS];
  __shared__ int scn[BROWS];
  __shared__ int rcur[BROWS];
  __shared__ int2 stg[CAP];
  int b = blockIdx.x;
  int t = threadIdx.x;
  int base = bbase[b], cnt = bbase[b + 1] - base;
  int rows = min(BROWS, N - b * BROWS);
  rcnt[t] = 0;
  __syncthreads();
  for (int i = t; i < cnt; i += 256) {
    int2 e = bucketed[base + i];
    atomicAdd(&rcnt[e.x >> 17], 1);
  }
  __syncthreads();
  scn[t] = rcnt[t];
  __syncthreads();
  for (int off = 1; off < 256; off <<= 1) {
    int v = (t >= off) ? scn[t - off] : 0;
    __syncthreads();
    scn[t] += v;
    __syncthreads();
  }
  int excl = scn[t] - rcnt[t];
  rcur[t] = excl;
  if (t < rows) rowptr[b * BROWS + t] = base + excl;
  __syncthreads();
  for (int i = t; i < cnt; i += 256) {
    int2 e = bucketed[base + i];
    int pos = atomicAdd(&rcur[e.x >> 17], 1);
    if (pos < CAP) stg[pos] = make_int2(e.x & 0x1FFFF, e.y);
  }
  __syncthreads();
  for (int i = t; i < cnt; i += 256) cv[base + i] = stg[i];
}

// ------ SpMM1 (algebraic): ax[r] = (sum v*x[c], sum v)  -> float4 [N] --------
// one 16-lane group per row; lane = edge slot; butterfly reduce.
__global__ __launch_bounds__(256) void spmm1_ax_k(
    const int* __restrict__ rowptr, const int2* __restrict__ cv,
    const float* __restrict__ x, float4* __restrict__ out4, int N) {
  int gw = (blockIdx.x * 256 + threadIdx.x) >> 4;  // row id (16-lane group)
  int L = threadIdx.x & 15;
  if (gw >= N) return;
  int s = rowptr[gw], e = rowptr[gw + 1];
  float a0 = 0.f, a1 = 0.f, a2 = 0.f, a3 = 0.f;
  for (int i = s + L; i < e; i += 16) {
    int2 p = cv[i];
    const float* xp = x + 3 * (size_t)p.x;
    float v = __int_as_float(p.y);
    float x0 = xp[0], x1 = xp[1], x2 = xp[2];
    a0 = fmaf(v, x0, a0);
    a1 = fmaf(v, x1, a1);
    a2 = fmaf(v, x2, a2);
    a3 += v;
  }
#pragma unroll
  for (int msk = 8; msk >= 1; msk >>= 1) {
    a0 += __shfl_xor(a0, msk, 64);
    a1 += __shfl_xor(a1, msk, 64);
    a2 += __shfl_xor(a2, msk, 64);
    a3 += __shfl_xor(a3, msk, 64);
  }
  if (L == 0) out4[gw] = make_float4(a0, a1, a2, a3);
}

// --- BN1 + ReLU + W1-fold fused into (.)@W2 + b2; bf16 output ----------------
// h1[n][f] = ax0*W1[0][f] + ax1*W1[1][f] + ax2*W1[2][f] + deg*b1[f]
__global__ __launch_bounds__(256) void bn_mm_k(
    const float4* __restrict__ ax,
    const float* __restrict__ W1, const float* __restrict__ b1,
    const float* __restrict__ g, const float* __restrict__ be,
    const float* __restrict__ m, const float* __restrict__ v,
    const float* __restrict__ W2, const float* __restrict__ b2,
    __hip_bfloat16* __restrict__ out, int N) {
  __shared__ float sW[HID][HID];
  __shared__ float sh[4][HID];
  int tid = threadIdx.x;
  int f = tid & (HID - 1);
  int q = tid >> 6;
  for (int i = tid; i < HID * HID; i += 256) sW[i >> 6][i & (HID - 1)] = W2[i];
  float w10 = W1[0 * HID + f], w11 = W1[1 * HID + f], w12 = W1[2 * HID + f];
  float b1f = b1[f];
  float scale = g[f] * rsqrtf(v[f] + BN_EPS);
  float shift = fmaf(-m[f], scale, be[f]);
  float bias = b2[f];
  int nbase = blockIdx.x * 64;
  for (int it = 0; it < 16; ++it) {
    int n = nbase + it * 4 + q;
    __syncthreads();
    float hv = 0.f;
    if (n < N) {
      float4 a = ax[n];
      hv = fmaf(a.x, w10, fmaf(a.y, w11, fmaf(a.z, w12, a.w * b1f)));
    }
    sh[q][f] = fmaxf(fmaf(hv, scale, shift), 0.f);
    __syncthreads();
    if (n < N) {
      float acc = bias;
#pragma unroll
      for (int k = 0; k < HID; ++k) acc = fmaf(sh[q][k], sW[k][f], acc);
      out[(size_t)n * HID + f] = __float2bfloat16(acc);
    }
  }
}

// ---- SpMM2 (bf16 gather, unroll-16) fused with BN2 + ReLU + mean/max pool ---
__global__ __launch_bounds__(256) void spmm2_pool_k(
    const int* __restrict__ rowptr, const int2* __restrict__ cv,
    const __hip_bfloat16* __restrict__ h,
    const float* __restrict__ g, const float* __restrict__ be,
    const float* __restrict__ m, const float* __restrict__ v,
    float* __restrict__ gsum, unsigned* __restrict__ gmax, int N) {
  int lane = threadIdx.x & 63;
  int wid = threadIdx.x >> 6;
  float scale = g[lane] * rsqrtf(v[lane] + BN_EPS);
  float shift = fmaf(-m[lane], scale, be[lane]);
  float psum = 0.f, pmax = 0.f;
  int stride = gridDim.x * 4;
  for (int r = blockIdx.x * 4 + wid; r < N; r += stride) {
    int s = rowptr[r], e = rowptr[r + 1];
    float acc = 0.f;
    int i = s;
    for (; i + 16 <= e; i += 16) {
      int2 p[16];
#pragma unroll
      for (int j = 0; j < 16; ++j) p[j] = cv[i + j];
      float a[16];
#pragma unroll
      for (int j = 0; j < 16; ++j)
        a[j] = __bfloat162float(h[(size_t)p[j].x * HID + lane]);
#pragma unroll
      for (int j = 0; j < 16; ++j)
        acc = fmaf(__int_as_float(p[j].y), a[j], acc);
    }
    for (; i + 4 <= e; i += 4) {
      int2 p[4];
#pragma unroll
      for (int j = 0; j < 4; ++j) p[j] = cv[i + j];
      float a[4];
#pragma unroll
      for (int j = 0; j < 4; ++j)
        a[j] = __bfloat162float(h[(size_t)p[j].x * HID + lane]);
#pragma unroll
      for (int j = 0; j < 4; ++j)
        acc = fmaf(__int_as_float(p[j].y), a[j], acc);
    }
    for (; i < e; ++i) {
      int2 p = cv[i];
      acc = fmaf(__int_as_float(p.y),
                 __bfloat162float(h[(size_t)p.x * HID + lane]), acc);
    }
    float hv = fmaxf(fmaf(acc, scale, shift), 0.f);
    psum += hv;
    pmax = fmaxf(pmax, hv);
  }
  __shared__ float ls[4][HID], lm[4][HID];
  ls[wid][lane] = psum;
  lm[wid][lane] = pmax;
  __syncthreads();
  if (wid == 0) {
    float s4 = ls[0][lane] + ls[1][lane] + ls[2][lane] + ls[3][lane];
    float m4 = fmaxf(fmaxf(lm[0][lane], lm[1][lane]),
                     fmaxf(lm[2][lane], lm[3][lane]));
    atomicAdd(&gsum[lane], s4);
    atomicMax(&gmax[lane], __float_as_uint(m4));
  }
}

// ------------- final: out = concat(mean, max) @ Wc + bc ----------------------
__global__ __launch_bounds__(128) void final_k(
    const float* __restrict__ gsum, const unsigned* __restrict__ gmax,
    const float* __restrict__ Wc, const float* __restrict__ bc,
    float* __restrict__ out, float invN) {
  __shared__ float red[128 * 3];
  int j = threadIdx.x;
  float gj = (j < HID) ? gsum[j] * invN : __uint_as_float(gmax[j - HID]);
#pragma unroll
  for (int c = 0; c < 3; ++c) red[j * 3 + c] = gj * Wc[j * 3 + c];
  __syncthreads();
  for (int off = 64; off >= 1; off >>= 1) {
    if (j < off) {
#pragma unroll
      for (int c = 0; c < 3; ++c) red[j * 3 + c] += red[(j + off) * 3 + c];
    }
    __syncthreads();
  }
  if (j < 3) out[j] = red[j] + bc[j];
}

extern "C" void kernel_launch(void* const* d_in, const int* in_sizes, int n_in,
                              void* d_out, int out_size, void* d_ws, size_t ws_size,
                              hipStream_t stream) {
  const float* x    = (const float*)d_in[0];
  const int*   row  = (const int*)d_in[1];
  const int*   col  = (const int*)d_in[2];
  const float* vals = (const float*)d_in[3];
  const float* W1   = (const float*)d_in[4];
  const float* b1   = (const float*)d_in[5];
  const float* g1   = (const float*)d_in[6];
  const float* be1  = (const float*)d_in[7];
  const float* m1   = (const float*)d_in[8];
  const float* v1   = (const float*)d_in[9];
  const float* W2   = (const float*)d_in[10];
  const float* b2   = (const float*)d_in[11];
  const float* g2   = (const float*)d_in[12];
  const float* be2  = (const float*)d_in[13];
  const float* m2   = (const float*)d_in[14];
  const float* v2   = (const float*)d_in[15];
  const float* Wc   = (const float*)d_in[16];
  const float* bc   = (const float*)d_in[17];
  float* out = (float*)d_out;

  const int N = in_sizes[0] / 3;
  const int E = in_sizes[1];
  const int NB = (N + BROWS - 1) / BROWS;

  // ---- workspace layout ----
  float4* ax = (float4*)d_ws;                                 // N float4
  __hip_bfloat16* wsA = (__hip_bfloat16*)(ax + N);            // N*64 bf16
  int2* bucketed = (int2*)(wsA + (size_t)N * HID);            // E
  int2* cv = bucketed + E;                                    // E
  int* rowptr = (int*)(cv + E);                               // N+2
  int* bhist = rowptr + (N + 2);                              // MAXB
  int* bbase = bhist + MAXB;                                  // MAXB+1
  int* bcur  = bbase + MAXB + 1;                              // MAXB
  float* gsum = (float*)(bcur + MAXB + 1);                    // 64
  unsigned* gmax = (unsigned*)(gsum + HID);                   // 64

  // ---- build row-sorted edge list (bucketed LDS sort, coalesced writes) ----
  hipMemsetAsync(bhist, 0, MAXB * sizeof(int), stream);
  bhist_k<<<512, 256, 0, stream>>>(row, bhist, E, NB);
  bscan_k<<<1, 256, 0, stream>>>(bhist, bbase, bcur, rowptr, NB, N, E);
  bucketA_k<<<(E + BATCH - 1) / BATCH, 256, 0, stream>>>(row, col, vals, bcur, bucketed, E, NB);
  bucketB_k<<<NB, 256, 0, stream>>>(bucketed, bbase, cv, rowptr, N);

  // ---- spmm1 (algebraic): ax = [A@x | A@1] ----
  spmm1_ax_k<<<(N * 16 + 255) / 256, 256, 0, stream>>>(rowptr, cv, x, ax, N);
  // ---- wsA = bf16( relu(bn1(ax@W1 + deg*b1)) @ W2 + b2 ) ----
  bn_mm_k<<<(N + 63) / 64, 256, 0, stream>>>(ax, W1, b1, g1, be1, m1, v1, W2, b2, wsA, N);
  // ---- spmm2 fused with BN2+ReLU+pool (bf16 gather, unroll-16) ----
  hipMemsetAsync(gsum, 0, 2 * HID * sizeof(float), stream);
  spmm2_pool_k<<<2048, 256, 0, stream>>>(rowptr, cv, wsA, g2, be2, m2, v2, gsum, gmax, N);
  // ---- out = concat(mean,max) @ Wc + bc ----
  final_k<<<1, 128, 0, stream>>>(gsum, gmax, Wc, bc, out, 1.0f / (float)N);
}

// Round 6
// 244.606 us; speedup vs baseline: 11.4988x; 1.0805x over previous
//
#include <hip/hip_runtime.h>
#include <hip/hip_bf16.h>

#define HID 64
#define BN_EPS 1e-5f
#define BROWS 256          // rows per bucket
#define MAXB 512           // max buckets (N <= 131072)
#define BATCH 8192         // edges per pass-A block
#define CAP 8192           // pass-B LDS staging slots

// ---------------- bucket histogram (LDS pre-aggregated) ----------------------
__global__ __launch_bounds__(256) void bhist_k(
    const int* __restrict__ row, int* __restrict__ bhist, int E, int NB) {
  __shared__ int lcnt[MAXB];
  for (int i = threadIdx.x; i < MAXB; i += 256) lcnt[i] = 0;
  __syncthreads();
  int stride = gridDim.x * 256;
  for (int i = blockIdx.x * 256 + threadIdx.x; i < E; i += stride)
    atomicAdd(&lcnt[row[i] >> 8], 1);
  __syncthreads();
  for (int i = threadIdx.x; i < NB; i += 256)
    if (lcnt[i]) atomicAdd(&bhist[i], lcnt[i]);
}

// ---------------- bucket exclusive scan (single block) -----------------------
__global__ __launch_bounds__(256) void bscan_k(
    const int* __restrict__ bhist, int* __restrict__ bbase,
    int* __restrict__ bcur, int* __restrict__ rowptr, int NB, int N, int E) {
  __shared__ int scn[512];
  __shared__ int orig[512];
  int t = threadIdx.x;
  int i0 = t, i1 = t + 256;
  int v0 = (i0 < NB) ? bhist[i0] : 0;
  int v1 = (i1 < NB) ? bhist[i1] : 0;
  scn[i0] = v0; orig[i0] = v0;
  scn[i1] = v1; orig[i1] = v1;
  __syncthreads();
  for (int off = 1; off < 512; off <<= 1) {
    int a0 = (i0 >= off) ? scn[i0 - off] : 0;
    int a1 = (i1 >= off) ? scn[i1 - off] : 0;
    __syncthreads();
    scn[i0] += a0; scn[i1] += a1;
    __syncthreads();
  }
  if (i0 < NB) { int e = scn[i0] - orig[i0]; bbase[i0] = e; bcur[i0] = e; }
  if (i1 < NB) { int e = scn[i1] - orig[i1]; bbase[i1] = e; bcur[i1] = e; }
  if (t == 0) { bbase[NB] = E; rowptr[N] = E; }
}

// ------- pass A: LDS-staged binning of edges into bucket regions -------------
// packed entry: .x = (localrow<<17) | col,  .y = val bits
__global__ __launch_bounds__(256) void bucketA_k(
    const int* __restrict__ row, const int* __restrict__ col,
    const float* __restrict__ vals, int* __restrict__ bcur,
    int2* __restrict__ bucketed, int E, int NB) {
  __shared__ int cnt[512];
  __shared__ int scn[512];
  __shared__ int cnt2[512];
  __shared__ int gbase[512];
  __shared__ int2 stg[BATCH];
  __shared__ unsigned short stgb[BATCH];
  int t = threadIdx.x;
  int start = blockIdx.x * BATCH;
  for (int i = t; i < 512; i += 256) { cnt[i] = 0; }
  __syncthreads();
#pragma unroll
  for (int k = 0; k < BATCH / 256; ++k) {
    int i = start + k * 256 + t;
    if (i < E) atomicAdd(&cnt[row[i] >> 8], 1);
  }
  __syncthreads();
  int i0 = t, i1 = t + 256;
  scn[i0] = cnt[i0]; scn[i1] = cnt[i1];
  __syncthreads();
  for (int off = 1; off < 512; off <<= 1) {
    int a0 = (i0 >= off) ? scn[i0 - off] : 0;
    int a1 = (i1 >= off) ? scn[i1 - off] : 0;
    __syncthreads();
    scn[i0] += a0; scn[i1] += a1;
    __syncthreads();
  }
  cnt2[i0] = scn[i0] - cnt[i0];
  cnt2[i1] = scn[i1] - cnt[i1];
  for (int b = t; b < NB; b += 256)
    if (cnt[b] > 0) gbase[b] = atomicAdd(&bcur[b], cnt[b]);
  __syncthreads();
#pragma unroll
  for (int k = 0; k < BATCH / 256; ++k) {
    int i = start + k * 256 + t;
    if (i < E) {
      int r = row[i];
      int b = r >> 8;
      int pos = atomicAdd(&cnt2[b], 1);
      stg[pos] = make_int2(((r & 255) << 17) | col[i], __float_as_int(vals[i]));
      stgb[pos] = (unsigned short)b;
    }
  }
  __syncthreads();
  int m = min(BATCH, E - start);
  for (int s = t; s < m; s += 256) {
    int b = stgb[s];
    int lbase = scn[b] - cnt[b];
    bucketed[gbase[b] + (s - lbase)] = stg[s];
  }
}

// ------- pass B: per-bucket LDS sort by row; write cv + rowptr ---------------
__global__ __launch_bounds__(256) void bucketB_k(
    const int2* __restrict__ bucketed, const int* __restrict__ bbase,
    int2* __restrict__ cv, int* __restrict__ rowptr, int N) {
  __shared__ int rcnt[BROWS];
  __shared__ int scn[BROWS];
  __shared__ int rcur[BROWS];
  __shared__ int2 stg[CAP];
  int b = blockIdx.x;
  int t = threadIdx.x;
  int base = bbase[b], cnt = bbase[b + 1] - base;
  int rows = min(BROWS, N - b * BROWS);
  rcnt[t] = 0;
  __syncthreads();
  for (int i = t; i < cnt; i += 256) {
    int2 e = bucketed[base + i];
    atomicAdd(&rcnt[e.x >> 17], 1);
  }
  __syncthreads();
  scn[t] = rcnt[t];
  __syncthreads();
  for (int off = 1; off < 256; off <<= 1) {
    int v = (t >= off) ? scn[t - off] : 0;
    __syncthreads();
    scn[t] += v;
    __syncthreads();
  }
  int excl = scn[t] - rcnt[t];
  rcur[t] = excl;
  if (t < rows) rowptr[b * BROWS + t] = base + excl;
  __syncthreads();
  for (int i = t; i < cnt; i += 256) {
    int2 e = bucketed[base + i];
    int pos = atomicAdd(&rcur[e.x >> 17], 1);
    if (pos < CAP) stg[pos] = make_int2(e.x & 0x1FFFF, e.y);
  }
  __syncthreads();
  for (int i = t; i < cnt; i += 256) cv[base + i] = stg[i];
}

// ------ SpMM1 (algebraic): ax[r] = (sum v*x[c], sum v)  -> float4 [N] --------
__global__ __launch_bounds__(256) void spmm1_ax_k(
    const int* __restrict__ rowptr, const int2* __restrict__ cv,
    const float* __restrict__ x, float4* __restrict__ out4, int N) {
  int gw = (blockIdx.x * 256 + threadIdx.x) >> 4;  // row id (16-lane group)
  int L = threadIdx.x & 15;
  if (gw >= N) return;
  int s = rowptr[gw], e = rowptr[gw + 1];
  float a0 = 0.f, a1 = 0.f, a2 = 0.f, a3 = 0.f;
  for (int i = s + L; i < e; i += 16) {
    int2 p = cv[i];
    const float* xp = x + 3 * (size_t)p.x;
    float v = __int_as_float(p.y);
    float x0 = xp[0], x1 = xp[1], x2 = xp[2];
    a0 = fmaf(v, x0, a0);
    a1 = fmaf(v, x1, a1);
    a2 = fmaf(v, x2, a2);
    a3 += v;
  }
#pragma unroll
  for (int msk = 8; msk >= 1; msk >>= 1) {
    a0 += __shfl_xor(a0, msk, 64);
    a1 += __shfl_xor(a1, msk, 64);
    a2 += __shfl_xor(a2, msk, 64);
    a3 += __shfl_xor(a3, msk, 64);
  }
  if (L == 0) out4[gw] = make_float4(a0, a1, a2, a3);
}

// --- BN1 + ReLU + W1-fold fused into (.)@W2 + b2; bf16 output ----------------
__global__ __launch_bounds__(256) void bn_mm_k(
    const float4* __restrict__ ax,
    const float* __restrict__ W1, const float* __restrict__ b1,
    const float* __restrict__ g, const float* __restrict__ be,
    const float* __restrict__ m, const float* __restrict__ v,
    const float* __restrict__ W2, const float* __restrict__ b2,
    __hip_bfloat16* __restrict__ out, int N) {
  __shared__ float sW[HID][HID];
  __shared__ float sh[4][HID];
  int tid = threadIdx.x;
  int f = tid & (HID - 1);
  int q = tid >> 6;
  for (int i = tid; i < HID * HID; i += 256) sW[i >> 6][i & (HID - 1)] = W2[i];
  float w10 = W1[0 * HID + f], w11 = W1[1 * HID + f], w12 = W1[2 * HID + f];
  float b1f = b1[f];
  float scale = g[f] * rsqrtf(v[f] + BN_EPS);
  float shift = fmaf(-m[f], scale, be[f]);
  float bias = b2[f];
  int nbase = blockIdx.x * 64;
  for (int it = 0; it < 16; ++it) {
    int n = nbase + it * 4 + q;
    __syncthreads();
    float hv = 0.f;
    if (n < N) {
      float4 a = ax[n];
      hv = fmaf(a.x, w10, fmaf(a.y, w11, fmaf(a.z, w12, a.w * b1f)));
    }
    sh[q][f] = fmaxf(fmaf(hv, scale, shift), 0.f);
    __syncthreads();
    if (n < N) {
      float acc = bias;
#pragma unroll
      for (int k = 0; k < HID; ++k) acc = fmaf(sh[q][k], sW[k][f], acc);
      out[(size_t)n * HID + f] = __float2bfloat16(acc);
    }
  }
}

// ---- SpMM2: 2 edges/wave-step, bf16x2 per lane; fused BN2+ReLU+pool ---------
// lane = 32*half + fl; half picks edge parity, fl picks feature pair (2fl,2fl+1)
__global__ __launch_bounds__(256) void spmm2_pool_k(
    const int* __restrict__ rowptr, const int2* __restrict__ cv,
    const __hip_bfloat16* __restrict__ hb,
    const float* __restrict__ g, const float* __restrict__ be,
    const float* __restrict__ m, const float* __restrict__ v,
    float* __restrict__ gsum, unsigned* __restrict__ gmax, int N) {
  int lane = threadIdx.x & 63;
  int wid = threadIdx.x >> 6;
  int half = lane >> 5;        // 0: even edge, 1: odd edge
  int fl = lane & 31;          // feature pair
  int f0 = 2 * fl, f1 = 2 * fl + 1;
  float scale0 = g[f0] * rsqrtf(v[f0] + BN_EPS);
  float shift0 = fmaf(-m[f0], scale0, be[f0]);
  float scale1 = g[f1] * rsqrtf(v[f1] + BN_EPS);
  float shift1 = fmaf(-m[f1], scale1, be[f1]);
  const uint* __restrict__ h32 = (const uint*)hb;  // h row = 32 uints
  float psum0 = 0.f, psum1 = 0.f, pmax0 = 0.f, pmax1 = 0.f;
  int stride = gridDim.x * 4;
  for (int r = blockIdx.x * 4 + wid; r < N; r += stride) {
    int s = rowptr[r], e = rowptr[r + 1];
    float acc0 = 0.f, acc1 = 0.f;
    int i = s;
    // main chunk: 8 edges = 4 gather slots/lane
    for (; i + 8 <= e; i += 8) {
      int2 q[8];
#pragma unroll
      for (int j = 0; j < 8; ++j) q[j] = cv[i + j];
      int cols[4]; float vv[4];
#pragma unroll
      for (int k = 0; k < 4; ++k) {
        int2 qa = q[2 * k], qb = q[2 * k + 1];
        cols[k] = half ? qb.x : qa.x;
        vv[k] = __int_as_float(half ? qb.y : qa.y);
      }
      uint hv[4];
#pragma unroll
      for (int k = 0; k < 4; ++k) hv[k] = h32[(size_t)cols[k] * 32 + fl];
#pragma unroll
      for (int k = 0; k < 4; ++k) {
        acc0 = fmaf(vv[k], __uint_as_float(hv[k] << 16), acc0);
        acc1 = fmaf(vv[k], __uint_as_float(hv[k] & 0xffff0000u), acc1);
      }
    }
    // 2-edge steps
    for (; i + 2 <= e; i += 2) {
      int2 qa = cv[i], qb = cv[i + 1];
      int c = half ? qb.x : qa.x;
      float vvv = __int_as_float(half ? qb.y : qa.y);
      uint hv = h32[(size_t)c * 32 + fl];
      acc0 = fmaf(vvv, __uint_as_float(hv << 16), acc0);
      acc1 = fmaf(vvv, __uint_as_float(hv & 0xffff0000u), acc1);
    }
    // single tail edge: upper half contributes 0
    if (i < e) {
      int2 qa = cv[i];
      float vvv = half ? 0.f : __int_as_float(qa.y);
      uint hv = h32[(size_t)qa.x * 32 + fl];
      acc0 = fmaf(vvv, __uint_as_float(hv << 16), acc0);
      acc1 = fmaf(vvv, __uint_as_float(hv & 0xffff0000u), acc1);
    }
    // fold the two edge-parity halves
    acc0 += __shfl_xor(acc0, 32, 64);
    acc1 += __shfl_xor(acc1, 32, 64);
    float hv0 = fmaxf(fmaf(acc0, scale0, shift0), 0.f);
    float hv1 = fmaxf(fmaf(acc1, scale1, shift1), 0.f);
    psum0 += hv0; psum1 += hv1;
    pmax0 = fmaxf(pmax0, hv0); pmax1 = fmaxf(pmax1, hv1);
  }
  __shared__ float ls[4][HID], lm[4][HID];
  if (half == 0) {
    ls[wid][f0] = psum0; ls[wid][f1] = psum1;
    lm[wid][f0] = pmax0; lm[wid][f1] = pmax1;
  }
  __syncthreads();
  int t = threadIdx.x;
  if (t < HID) {
    float s4 = ls[0][t] + ls[1][t] + ls[2][t] + ls[3][t];
    float m4 = fmaxf(fmaxf(lm[0][t], lm[1][t]), fmaxf(lm[2][t], lm[3][t]));
    atomicAdd(&gsum[t], s4);
    atomicMax(&gmax[t], __float_as_uint(m4));
  }
}

// ------------- final: out = concat(mean, max) @ Wc + bc ----------------------
__global__ __launch_bounds__(128) void final_k(
    const float* __restrict__ gsum, const unsigned* __restrict__ gmax,
    const float* __restrict__ Wc, const float* __restrict__ bc,
    float* __restrict__ out, float invN) {
  __shared__ float red[128 * 3];
  int j = threadIdx.x;
  float gj = (j < HID) ? gsum[j] * invN : __uint_as_float(gmax[j - HID]);
#pragma unroll
  for (int c = 0; c < 3; ++c) red[j * 3 + c] = gj * Wc[j * 3 + c];
  __syncthreads();
  for (int off = 64; off >= 1; off >>= 1) {
    if (j < off) {
#pragma unroll
      for (int c = 0; c < 3; ++c) red[j * 3 + c] += red[(j + off) * 3 + c];
    }
    __syncthreads();
  }
  if (j < 3) out[j] = red[j] + bc[j];
}

extern "C" void kernel_launch(void* const* d_in, const int* in_sizes, int n_in,
                              void* d_out, int out_size, void* d_ws, size_t ws_size,
                              hipStream_t stream) {
  const float* x    = (const float*)d_in[0];
  const int*   row  = (const int*)d_in[1];
  const int*   col  = (const int*)d_in[2];
  const float* vals = (const float*)d_in[3];
  const float* W1   = (const float*)d_in[4];
  const float* b1   = (const float*)d_in[5];
  const float* g1   = (const float*)d_in[6];
  const float* be1  = (const float*)d_in[7];
  const float* m1   = (const float*)d_in[8];
  const float* v1   = (const float*)d_in[9];
  const float* W2   = (const float*)d_in[10];
  const float* b2   = (const float*)d_in[11];
  const float* g2   = (const float*)d_in[12];
  const float* be2  = (const float*)d_in[13];
  const float* m2   = (const float*)d_in[14];
  const float* v2   = (const float*)d_in[15];
  const float* Wc   = (const float*)d_in[16];
  const float* bc   = (const float*)d_in[17];
  float* out = (float*)d_out;

  const int N = in_sizes[0] / 3;
  const int E = in_sizes[1];
  const int NB = (N + BROWS - 1) / BROWS;

  // ---- workspace layout ----
  float4* ax = (float4*)d_ws;                                 // N float4
  __hip_bfloat16* wsA = (__hip_bfloat16*)(ax + N);            // N*64 bf16
  int2* bucketed = (int2*)(wsA + (size_t)N * HID);            // E
  int2* cv = bucketed + E;                                    // E
  int* rowptr = (int*)(cv + E);                               // N+2
  int* bhist = rowptr + (N + 2);                              // MAXB
  int* bbase = bhist + MAXB;                                  // MAXB+1
  int* bcur  = bbase + MAXB + 1;                              // MAXB
  float* gsum = (float*)(bcur + MAXB + 1);                    // 64
  unsigned* gmax = (unsigned*)(gsum + HID);                   // 64

  // ---- build row-sorted edge list (bucketed LDS sort, coalesced writes) ----
  hipMemsetAsync(bhist, 0, MAXB * sizeof(int), stream);
  bhist_k<<<512, 256, 0, stream>>>(row, bhist, E, NB);
  bscan_k<<<1, 256, 0, stream>>>(bhist, bbase, bcur, rowptr, NB, N, E);
  bucketA_k<<<(E + BATCH - 1) / BATCH, 256, 0, stream>>>(row, col, vals, bcur, bucketed, E, NB);
  bucketB_k<<<NB, 256, 0, stream>>>(bucketed, bbase, cv, rowptr, N);

  // ---- spmm1 (algebraic): ax = [A@x | A@1] ----
  spmm1_ax_k<<<(N * 16 + 255) / 256, 256, 0, stream>>>(rowptr, cv, x, ax, N);
  // ---- wsA = bf16( relu(bn1(ax@W1 + deg*b1)) @ W2 + b2 ) ----
  bn_mm_k<<<(N + 63) / 64, 256, 0, stream>>>(ax, W1, b1, g1, be1, m1, v1, W2, b2, wsA, N);
  // ---- spmm2 fused with BN2+ReLU+pool (bf16x2, 2 edges/step) ----
  hipMemsetAsync(gsum, 0, 2 * HID * sizeof(float), stream);
  spmm2_pool_k<<<2048, 256, 0, stream>>>(rowptr, cv, wsA, g2, be2, m2, v2, gsum, gmax, N);
  // ---- out = concat(mean,max) @ Wc + bc ----
  final_k<<<1, 128, 0, stream>>>(gsum, gmax, Wc, bc, out, 1.0f / (float)N);
}

// Round 7
// 231.615 us; speedup vs baseline: 12.1437x; 1.0561x over previous
//
#include <hip/hip_runtime.h>
#include <hip/hip_bf16.h>

#define HID 64
#define BN_EPS 1e-5f
#define BROWS 256          // rows per bucket
#define MAXB 512           // max buckets (N <= 131072)
#define BATCH 8192         // edges per pass-A block
#define CAP 8192           // pass-B LDS staging slots
#define S2GRID 2048        // spmm2 grid (blocks)

// ---------------- bucket histogram (LDS pre-aggregated) ----------------------
__global__ __launch_bounds__(256) void bhist_k(
    const int* __restrict__ row, int* __restrict__ bhist, int E, int NB) {
  __shared__ int lcnt[MAXB];
  for (int i = threadIdx.x; i < MAXB; i += 256) lcnt[i] = 0;
  __syncthreads();
  int stride = gridDim.x * 256;
  for (int i = blockIdx.x * 256 + threadIdx.x; i < E; i += stride)
    atomicAdd(&lcnt[row[i] >> 8], 1);
  __syncthreads();
  for (int i = threadIdx.x; i < NB; i += 256)
    if (lcnt[i]) atomicAdd(&bhist[i], lcnt[i]);
}

// ---------------- bucket exclusive scan (single block) -----------------------
__global__ __launch_bounds__(256) void bscan_k(
    const int* __restrict__ bhist, int* __restrict__ bbase,
    int* __restrict__ bcur, int* __restrict__ rowptr, int NB, int N, int E) {
  __shared__ int scn[512];
  __shared__ int orig[512];
  int t = threadIdx.x;
  int i0 = t, i1 = t + 256;
  int v0 = (i0 < NB) ? bhist[i0] : 0;
  int v1 = (i1 < NB) ? bhist[i1] : 0;
  scn[i0] = v0; orig[i0] = v0;
  scn[i1] = v1; orig[i1] = v1;
  __syncthreads();
  for (int off = 1; off < 512; off <<= 1) {
    int a0 = (i0 >= off) ? scn[i0 - off] : 0;
    int a1 = (i1 >= off) ? scn[i1 - off] : 0;
    __syncthreads();
    scn[i0] += a0; scn[i1] += a1;
    __syncthreads();
  }
  if (i0 < NB) { int e = scn[i0] - orig[i0]; bbase[i0] = e; bcur[i0] = e; }
  if (i1 < NB) { int e = scn[i1] - orig[i1]; bbase[i1] = e; bcur[i1] = e; }
  if (t == 0) { bbase[NB] = E; rowptr[N] = E; }
}

// ------- pass A: LDS-staged binning of edges into bucket regions -------------
// packed entry: .x = (localrow<<17) | col,  .y = val bits
__global__ __launch_bounds__(256) void bucketA_k(
    const int* __restrict__ row, const int* __restrict__ col,
    const float* __restrict__ vals, int* __restrict__ bcur,
    int2* __restrict__ bucketed, int E, int NB) {
  __shared__ int cnt[512];
  __shared__ int scn[512];
  __shared__ int cnt2[512];
  __shared__ int gbase[512];
  __shared__ int2 stg[BATCH];
  __shared__ unsigned short stgb[BATCH];
  int t = threadIdx.x;
  int start = blockIdx.x * BATCH;
  for (int i = t; i < 512; i += 256) { cnt[i] = 0; }
  __syncthreads();
#pragma unroll
  for (int k = 0; k < BATCH / 256; ++k) {
    int i = start + k * 256 + t;
    if (i < E) atomicAdd(&cnt[row[i] >> 8], 1);
  }
  __syncthreads();
  int i0 = t, i1 = t + 256;
  scn[i0] = cnt[i0]; scn[i1] = cnt[i1];
  __syncthreads();
  for (int off = 1; off < 512; off <<= 1) {
    int a0 = (i0 >= off) ? scn[i0 - off] : 0;
    int a1 = (i1 >= off) ? scn[i1 - off] : 0;
    __syncthreads();
    scn[i0] += a0; scn[i1] += a1;
    __syncthreads();
  }
  cnt2[i0] = scn[i0] - cnt[i0];
  cnt2[i1] = scn[i1] - cnt[i1];
  for (int b = t; b < NB; b += 256)
    if (cnt[b] > 0) gbase[b] = atomicAdd(&bcur[b], cnt[b]);
  __syncthreads();
#pragma unroll
  for (int k = 0; k < BATCH / 256; ++k) {
    int i = start + k * 256 + t;
    if (i < E) {
      int r = row[i];
      int b = r >> 8;
      int pos = atomicAdd(&cnt2[b], 1);
      stg[pos] = make_int2(((r & 255) << 17) | col[i], __float_as_int(vals[i]));
      stgb[pos] = (unsigned short)b;
    }
  }
  __syncthreads();
  int m = min(BATCH, E - start);
  for (int s = t; s < m; s += 256) {
    int b = stgb[s];
    int lbase = scn[b] - cnt[b];
    bucketed[gbase[b] + (s - lbase)] = stg[s];
  }
}

// --- pass B: per-bucket LDS sort by row; write cv + rowptr; compute ax -------
// ax[r] = (sum v*x[c] (3), sum v)  directly from the sorted LDS staging.
__global__ __launch_bounds__(256) void bucketB_k(
    const int2* __restrict__ bucketed, const int* __restrict__ bbase,
    const float* __restrict__ x,
    int2* __restrict__ cv, int* __restrict__ rowptr,
    float4* __restrict__ ax4, int N) {
  __shared__ int rcnt[BROWS];
  __shared__ int scn[BROWS];
  __shared__ int rcur[BROWS];
  __shared__ int2 stg[CAP];
  int b = blockIdx.x;
  int t = threadIdx.x;
  int base = bbase[b], cnt = bbase[b + 1] - base;
  int rows = min(BROWS, N - b * BROWS);
  rcnt[t] = 0;
  __syncthreads();
  for (int i = t; i < cnt; i += 256) {
    int2 e = bucketed[base + i];
    atomicAdd(&rcnt[e.x >> 17], 1);
  }
  __syncthreads();
  scn[t] = rcnt[t];
  __syncthreads();
  for (int off = 1; off < 256; off <<= 1) {
    int v = (t >= off) ? scn[t - off] : 0;
    __syncthreads();
    scn[t] += v;
    __syncthreads();
  }
  int excl = scn[t] - rcnt[t];
  rcur[t] = excl;
  if (t < rows) rowptr[b * BROWS + t] = base + excl;
  __syncthreads();
  for (int i = t; i < cnt; i += 256) {
    int2 e = bucketed[base + i];
    int pos = atomicAdd(&rcur[e.x >> 17], 1);
    if (pos < CAP) stg[pos] = make_int2(e.x & 0x1FFFF, e.y);
  }
  __syncthreads();
  for (int i = t; i < cnt; i += 256) cv[base + i] = stg[i];
  // ---- ax for this bucket's rows: 16-lane group per row, 16 passes ----
  int grp = t >> 4, L = t & 15;
  for (int pass = 0; pass < 16; ++pass) {
    int lrow = pass * 16 + grp;
    int s0 = scn[lrow] - rcnt[lrow];
    int e0 = scn[lrow];
    float a0 = 0.f, a1 = 0.f, a2 = 0.f, a3 = 0.f;
    for (int i2 = s0 + L; i2 < e0; i2 += 16) {
      int2 eg = stg[i2];
      const float* xp = x + 3 * (size_t)eg.x;
      float vv = __int_as_float(eg.y);
      a0 = fmaf(vv, xp[0], a0);
      a1 = fmaf(vv, xp[1], a1);
      a2 = fmaf(vv, xp[2], a2);
      a3 += vv;
    }
#pragma unroll
    for (int msk = 8; msk >= 1; msk >>= 1) {
      a0 += __shfl_xor(a0, msk, 64);
      a1 += __shfl_xor(a1, msk, 64);
      a2 += __shfl_xor(a2, msk, 64);
      a3 += __shfl_xor(a3, msk, 64);
    }
    if (L == 0 && lrow < rows) ax4[b * BROWS + lrow] = make_float4(a0, a1, a2, a3);
  }
}

// --- BN1 + ReLU + W1-fold fused into (.)@W2 + b2; bf16 output ----------------
__global__ __launch_bounds__(256) void bn_mm_k(
    const float4* __restrict__ ax,
    const float* __restrict__ W1, const float* __restrict__ b1,
    const float* __restrict__ g, const float* __restrict__ be,
    const float* __restrict__ m, const float* __restrict__ v,
    const float* __restrict__ W2, const float* __restrict__ b2,
    __hip_bfloat16* __restrict__ out, int N) {
  __shared__ float sW[HID][HID];
  __shared__ float sh[4][HID];
  int tid = threadIdx.x;
  int f = tid & (HID - 1);
  int q = tid >> 6;
  for (int i = tid; i < HID * HID; i += 256) sW[i >> 6][i & (HID - 1)] = W2[i];
  float w10 = W1[0 * HID + f], w11 = W1[1 * HID + f], w12 = W1[2 * HID + f];
  float b1f = b1[f];
  float scale = g[f] * rsqrtf(v[f] + BN_EPS);
  float shift = fmaf(-m[f], scale, be[f]);
  float bias = b2[f];
  int nbase = blockIdx.x * 64;
  for (int it = 0; it < 16; ++it) {
    int n = nbase + it * 4 + q;
    __syncthreads();
    float hv = 0.f;
    if (n < N) {
      float4 a = ax[n];
      hv = fmaf(a.x, w10, fmaf(a.y, w11, fmaf(a.z, w12, a.w * b1f)));
    }
    sh[q][f] = fmaxf(fmaf(hv, scale, shift), 0.f);
    __syncthreads();
    if (n < N) {
      float acc = bias;
#pragma unroll
      for (int k = 0; k < HID; ++k) acc = fmaf(sh[q][k], sW[k][f], acc);
      out[(size_t)n * HID + f] = __float2bfloat16(acc);
    }
  }
}

// ---- SpMM2: 2 independent rows per wave (32-lane halves), 2-deep pipeline ---
// lane = 32*half + fl; half owns row (pair*2+half); fl = feature pair (2fl,2fl+1)
__global__ __launch_bounds__(256) void spmm2_pool_k(
    const int* __restrict__ rowptr, const int2* __restrict__ cv,
    const __hip_bfloat16* __restrict__ hb,
    const float* __restrict__ g, const float* __restrict__ be,
    const float* __restrict__ m, const float* __restrict__ v,
    float* __restrict__ pS, float* __restrict__ pM, int N) {
  int lane = threadIdx.x & 63;
  int wid = threadIdx.x >> 6;
  int half = lane >> 5;
  int fl = lane & 31;
  int f0 = 2 * fl, f1 = 2 * fl + 1;
  float scale0 = g[f0] * rsqrtf(v[f0] + BN_EPS);
  float shift0 = fmaf(-m[f0], scale0, be[f0]);
  float scale1 = g[f1] * rsqrtf(v[f1] + BN_EPS);
  float shift1 = fmaf(-m[f1], scale1, be[f1]);
  const uint* __restrict__ h32 = (const uint*)hb;
  float psum0 = 0.f, psum1 = 0.f, pmax0 = 0.f, pmax1 = 0.f;
  int npairs = (N + 1) >> 1;
  int stride = gridDim.x * 4;
  for (int pr = blockIdx.x * 4 + wid; pr < npairs; pr += stride) {
    int rA = pr * 2, rB = rA + 1;
    int p0 = rowptr[rA];
    int p1 = rowptr[rA + 1];
    int p2 = (rB < N) ? rowptr[rB + 1] : p1;
    int my_s = half ? p1 : p0;
    int my_e = half ? p2 : p1;
    int remA = p1 - p0, remB = p2 - p1;
    int k = min(remA, remB) >> 2;  // 4-edge chunks per half (uniform)
    int i = my_s;
    float acc0 = 0.f, acc1 = 0.f;
    int2 qa0, qa1, qa2, qa3, qb0, qb1, qb2, qb3;
    if (k >= 1) { qa0 = cv[i]; qa1 = cv[i + 1]; qa2 = cv[i + 2]; qa3 = cv[i + 3]; }
    if (k >= 2) { qb0 = cv[i + 4]; qb1 = cv[i + 5]; qb2 = cv[i + 6]; qb3 = cv[i + 7]; }
    while (k >= 2) {
      uint h0 = h32[(size_t)qa0.x * 32 + fl];
      uint h1 = h32[(size_t)qa1.x * 32 + fl];
      uint h2_ = h32[(size_t)qa2.x * 32 + fl];
      uint h3 = h32[(size_t)qa3.x * 32 + fl];
      uint h4 = h32[(size_t)qb0.x * 32 + fl];
      uint h5 = h32[(size_t)qb1.x * 32 + fl];
      uint h6 = h32[(size_t)qb2.x * 32 + fl];
      uint h7 = h32[(size_t)qb3.x * 32 + fl];
      float v0 = __int_as_float(qa0.y), v1 = __int_as_float(qa1.y);
      float v2 = __int_as_float(qa2.y), v3 = __int_as_float(qa3.y);
      float v4 = __int_as_float(qb0.y), v5 = __int_as_float(qb1.y);
      float v6 = __int_as_float(qb2.y), v7 = __int_as_float(qb3.y);
      if (k >= 3) { qa0 = cv[i + 8]; qa1 = cv[i + 9]; qa2 = cv[i + 10]; qa3 = cv[i + 11]; }
      if (k >= 4) { qb0 = cv[i + 12]; qb1 = cv[i + 13]; qb2 = cv[i + 14]; qb3 = cv[i + 15]; }
      acc0 = fmaf(v0, __uint_as_float(h0 << 16), acc0);
      acc1 = fmaf(v0, __uint_as_float(h0 & 0xffff0000u), acc1);
      acc0 = fmaf(v1, __uint_as_float(h1 << 16), acc0);
      acc1 = fmaf(v1, __uint_as_float(h1 & 0xffff0000u), acc1);
      acc0 = fmaf(v2, __uint_as_float(h2_ << 16), acc0);
      acc1 = fmaf(v2, __uint_as_float(h2_ & 0xffff0000u), acc1);
      acc0 = fmaf(v3, __uint_as_float(h3 << 16), acc0);
      acc1 = fmaf(v3, __uint_as_float(h3 & 0xffff0000u), acc1);
      acc0 = fmaf(v4, __uint_as_float(h4 << 16), acc0);
      acc1 = fmaf(v4, __uint_as_float(h4 & 0xffff0000u), acc1);
      acc0 = fmaf(v5, __uint_as_float(h5 << 16), acc0);
      acc1 = fmaf(v5, __uint_as_float(h5 & 0xffff0000u), acc1);
      acc0 = fmaf(v6, __uint_as_float(h6 << 16), acc0);
      acc1 = fmaf(v6, __uint_as_float(h6 & 0xffff0000u), acc1);
      acc0 = fmaf(v7, __uint_as_float(h7 << 16), acc0);
      acc1 = fmaf(v7, __uint_as_float(h7 & 0xffff0000u), acc1);
      i += 8;
      k -= 2;
    }
    if (k == 1) {
      uint h0 = h32[(size_t)qa0.x * 32 + fl];
      uint h1 = h32[(size_t)qa1.x * 32 + fl];
      uint h2_ = h32[(size_t)qa2.x * 32 + fl];
      uint h3 = h32[(size_t)qa3.x * 32 + fl];
      acc0 = fmaf(__int_as_float(qa0.y), __uint_as_float(h0 << 16), acc0);
      acc1 = fmaf(__int_as_float(qa0.y), __uint_as_float(h0 & 0xffff0000u), acc1);
      acc0 = fmaf(__int_as_float(qa1.y), __uint_as_float(h1 << 16), acc0);
      acc1 = fmaf(__int_as_float(qa1.y), __uint_as_float(h1 & 0xffff0000u), acc1);
      acc0 = fmaf(__int_as_float(qa2.y), __uint_as_float(h2_ << 16), acc0);
      acc1 = fmaf(__int_as_float(qa2.y), __uint_as_float(h2_ & 0xffff0000u), acc1);
      acc0 = fmaf(__int_as_float(qa3.y), __uint_as_float(h3 << 16), acc0);
      acc1 = fmaf(__int_as_float(qa3.y), __uint_as_float(h3 & 0xffff0000u), acc1);
      i += 4;
    }
    // predicated singles tail (uniform step count across the wave)
    int myrem = my_e - i;
    int orem = __shfl_xor(myrem, 32, 64);
    int steps = max(myrem, orem);
    for (int s1 = 0; s1 < steps; ++s1) {
      bool act = (i < my_e);
      int2 q = make_int2(0, 0);
      if (act) q = cv[i];
      uint hq = h32[(size_t)q.x * 32 + fl];
      float vq = __int_as_float(q.y);
      acc0 = fmaf(vq, __uint_as_float(hq << 16), acc0);
      acc1 = fmaf(vq, __uint_as_float(hq & 0xffff0000u), acc1);
      ++i;
    }
    bool rvalid = (half == 0) || (rB < N);
    if (rvalid) {
      float hv0 = fmaxf(fmaf(acc0, scale0, shift0), 0.f);
      float hv1 = fmaxf(fmaf(acc1, scale1, shift1), 0.f);
      psum0 += hv0; psum1 += hv1;
      pmax0 = fmaxf(pmax0, hv0); pmax1 = fmaxf(pmax1, hv1);
    }
  }
  __shared__ float ls[8][HID], lm[8][HID];
  int slot = wid * 2 + half;
  ls[slot][f0] = psum0; ls[slot][f1] = psum1;
  lm[slot][f0] = pmax0; lm[slot][f1] = pmax1;
  __syncthreads();
  int t = threadIdx.x;
  if (t < HID) {
    float s8 = 0.f, m8 = 0.f;
#pragma unroll
    for (int kk = 0; kk < 8; ++kk) { s8 += ls[kk][t]; m8 = fmaxf(m8, lm[kk][t]); }
    pS[(size_t)t * S2GRID + blockIdx.x] = s8;
    pM[(size_t)t * S2GRID + blockIdx.x] = m8;
  }
}

// ---- reduce per-block pool partials: 64 blocks (one per feature) ------------
__global__ __launch_bounds__(256) void pool_reduce_k(
    const float* __restrict__ pS, const float* __restrict__ pM,
    float* __restrict__ gsum, float* __restrict__ gmaxf, int nblk) {
  int f = blockIdx.x;
  int t = threadIdx.x;
  float s = 0.f, m = 0.f;
  for (int j = t; j < nblk; j += 256) {
    s += pS[(size_t)f * nblk + j];
    m = fmaxf(m, pM[(size_t)f * nblk + j]);
  }
#pragma unroll
  for (int msk = 32; msk >= 1; msk >>= 1) {
    s += __shfl_xor(s, msk, 64);
    m = fmaxf(m, __shfl_xor(m, msk, 64));
  }
  __shared__ float ws_[4], wm_[4];
  if ((t & 63) == 0) { ws_[t >> 6] = s; wm_[t >> 6] = m; }
  __syncthreads();
  if (t == 0) {
    s = ws_[0] + ws_[1] + ws_[2] + ws_[3];
    m = fmaxf(fmaxf(wm_[0], wm_[1]), fmaxf(wm_[2], wm_[3]));
    gsum[f] = s;
    gmaxf[f] = m;
  }
}

// ------------- final: out = concat(mean, max) @ Wc + bc ----------------------
__global__ __launch_bounds__(128) void final_k(
    const float* __restrict__ gsum, const float* __restrict__ gmaxf,
    const float* __restrict__ Wc, const float* __restrict__ bc,
    float* __restrict__ out, float invN) {
  __shared__ float red[128 * 3];
  int j = threadIdx.x;
  float gj = (j < HID) ? gsum[j] * invN : gmaxf[j - HID];
#pragma unroll
  for (int c = 0; c < 3; ++c) red[j * 3 + c] = gj * Wc[j * 3 + c];
  __syncthreads();
  for (int off = 64; off >= 1; off >>= 1) {
    if (j < off) {
#pragma unroll
      for (int c = 0; c < 3; ++c) red[j * 3 + c] += red[(j + off) * 3 + c];
    }
    __syncthreads();
  }
  if (j < 3) out[j] = red[j] + bc[j];
}

extern "C" void kernel_launch(void* const* d_in, const int* in_sizes, int n_in,
                              void* d_out, int out_size, void* d_ws, size_t ws_size,
                              hipStream_t stream) {
  const float* x    = (const float*)d_in[0];
  const int*   row  = (const int*)d_in[1];
  const int*   col  = (const int*)d_in[2];
  const float* vals = (const float*)d_in[3];
  const float* W1   = (const float*)d_in[4];
  const float* b1   = (const float*)d_in[5];
  const float* g1   = (const float*)d_in[6];
  const float* be1  = (const float*)d_in[7];
  const float* m1   = (const float*)d_in[8];
  const float* v1   = (const float*)d_in[9];
  const float* W2   = (const float*)d_in[10];
  const float* b2   = (const float*)d_in[11];
  const float* g2   = (const float*)d_in[12];
  const float* be2  = (const float*)d_in[13];
  const float* m2   = (const float*)d_in[14];
  const float* v2   = (const float*)d_in[15];
  const float* Wc   = (const float*)d_in[16];
  const float* bc   = (const float*)d_in[17];
  float* out = (float*)d_out;

  const int N = in_sizes[0] / 3;
  const int E = in_sizes[1];
  const int NB = (N + BROWS - 1) / BROWS;

  // ---- workspace layout ----
  float4* ax = (float4*)d_ws;                                 // N float4
  __hip_bfloat16* wsA = (__hip_bfloat16*)(ax + N);            // N*64 bf16
  int2* bucketed = (int2*)(wsA + (size_t)N * HID);            // E
  int2* cv = bucketed + E;                                    // E
  int* rowptr = (int*)(cv + E);                               // N+2
  int* bhist = rowptr + (N + 2);                              // MAXB
  int* bbase = bhist + MAXB;                                  // MAXB+1
  int* bcur  = bbase + MAXB + 1;                              // MAXB
  float* pS = (float*)(bcur + MAXB + 1);                      // 64*S2GRID
  float* pM = pS + (size_t)HID * S2GRID;                      // 64*S2GRID
  float* gsum = pM + (size_t)HID * S2GRID;                    // 64
  float* gmaxf = gsum + HID;                                  // 64

  // ---- build row-sorted edge list + ax (bucketed LDS sort) ----
  hipMemsetAsync(bhist, 0, MAXB * sizeof(int), stream);
  bhist_k<<<512, 256, 0, stream>>>(row, bhist, E, NB);
  bscan_k<<<1, 256, 0, stream>>>(bhist, bbase, bcur, rowptr, NB, N, E);
  bucketA_k<<<(E + BATCH - 1) / BATCH, 256, 0, stream>>>(row, col, vals, bcur, bucketed, E, NB);
  bucketB_k<<<NB, 256, 0, stream>>>(bucketed, bbase, x, cv, rowptr, ax, N);

  // ---- wsA = bf16( relu(bn1(ax@W1 + deg*b1)) @ W2 + b2 ) ----
  bn_mm_k<<<(N + 63) / 64, 256, 0, stream>>>(ax, W1, b1, g1, be1, m1, v1, W2, b2, wsA, N);
  // ---- spmm2 fused with BN2+ReLU+pool (2 rows/wave, pipelined) ----
  spmm2_pool_k<<<S2GRID, 256, 0, stream>>>(rowptr, cv, wsA, g2, be2, m2, v2, pS, pM, N);
  pool_reduce_k<<<HID, 256, 0, stream>>>(pS, pM, gsum, gmaxf, S2GRID);
  // ---- out = concat(mean,max) @ Wc + bc ----
  final_k<<<1, 128, 0, stream>>>(gsum, gmaxf, Wc, bc, out, 1.0f / (float)N);
}